// Round 2
// baseline (9984.405 us; speedup 1.0000x reference)
//
#include <hip/hip_runtime.h>

#define DEV __device__ __forceinline__

// ---- problem dims ----
constexpr int B_ = 256, A_ = 20, T_ = 50, IN_ = 6;
constexpr int H_ = 256, G_ = 1024, NH_ = 8, DT_ = 60;
constexpr int NN_ = 19;
constexpr int NB_ = B_ * NN_;   // 4864 neighbor samples
constexpr int XROW = T_ * IN_;  // 300

// ---- encoder blocking: 22 samples/block, 512 thr (2 halves of 11 samples) ----
constexpr int MC = 22, MH = 11;
constexpr int NBLK_N = (NB_ + MC - 1) / MC;  // 222
constexpr int NBLK_E = (B_ + MC - 1) / MC;   // 12
constexpr int NBLK_ENC = NBLK_N + NBLK_E;    // 234  (<=256 -> 1 block/CU)
// ---- decoder blocking ----
constexpr int DM = 4, DMH = 2;
constexpr int NBLK_DEC = B_ / DM;            // 64

// ---- workspace layout (float offsets). Weights transposed to [k][4H] ----
constexpr size_t W1 = 256 * 1024;
constexpr size_t O_WT_N_HH0 = 0;
constexpr size_t O_WT_N_IH1 = O_WT_N_HH0 + W1;
constexpr size_t O_WT_N_HH1 = O_WT_N_IH1 + W1;
constexpr size_t O_WT_E_HH0 = O_WT_N_HH1 + W1;
constexpr size_t O_WT_E_IH1 = O_WT_E_HH0 + W1;
constexpr size_t O_WT_E_HH1 = O_WT_E_IH1 + W1;
constexpr size_t O_WT_D_HH0 = O_WT_E_HH1 + W1;
constexpr size_t O_WT_D_IH1 = O_WT_D_HH0 + W1;
constexpr size_t O_WT_D_HH1 = O_WT_D_IH1 + W1;
constexpr size_t O_WT_D_IH0 = O_WT_D_HH1 + W1;
constexpr size_t O_WT_N_IH0 = O_WT_D_IH0 + W1;        // [6][1024]
constexpr size_t O_WT_E_IH0 = O_WT_N_IH0 + 6 * 1024;  // [6][1024]
constexpr size_t O_BC       = O_WT_E_IH0 + 6 * 1024;  // 6 x 1024 (n0,n1,e0,e1,d0,d1) bih+bhh
constexpr size_t O_WT_Q  = O_BC + 6 * 1024;           // [k][256]
constexpr size_t O_WT_K  = O_WT_Q + 65536;
constexpr size_t O_WT_V  = O_WT_K + 65536;
constexpr size_t O_WT_AO = O_WT_V + 65536;
constexpr size_t O_WCT   = O_WT_AO + 65536;           // [2][512][256]
constexpr size_t O_NBR_H1 = O_WCT + 2 * 512 * 256;    // [2][4864][256] (t=48,49)
constexpr size_t O_COMB   = O_NBR_H1 + 2ull * NB_ * H_; // [2][256][512] ego|att
constexpr size_t O_PRE0   = O_COMB + 2ull * B_ * 512;   // [256][1024] decoder l0 x-part
constexpr size_t WS_FLOATS = O_PRE0 + (size_t)B_ * G_;  // ~6.18M floats (~24.7 MB)

struct Par {
  const float* x;
  const float* big_src[10];  // 1024x256 matrices to transpose, in ws order
  const float* ih0_src[2];   // nbr_Wih0, ego_Wih0 (1024x6)
  const float* att_src[4];   // Wq, Wk, Wv, Wao
  const float* Wconv;
  const float* bih[6];       // n0,n1,e0,e1,d0,d1
  const float* bhh[6];
  const float *bq, *bk, *bv, *bao, *bconv, *Wout, *bout;
  float* ws;
  float* out;
};

// ---------------- prep: transposes + bias sums ----------------
__global__ void prep_kernel(Par p) {
  const size_t NBIG = 10 * W1;
  const size_t NI0  = 2 * 6 * 1024;
  const size_t NATT = 4 * 65536;
  const size_t NCV  = 2 * 512 * 256;
  const size_t NBC  = 6 * 1024;
  const size_t total = NBIG + NI0 + NATT + NCV + NBC;
  for (size_t i = (size_t)blockIdx.x * blockDim.x + threadIdx.x; i < total;
       i += (size_t)gridDim.x * blockDim.x) {
    size_t idx = i;
    if (idx < NBIG) {  // Wt[k][r] = W[r][k], 10 matrices contiguous from 0
      int mi = (int)(idx / W1);
      size_t e = idx - (size_t)mi * W1;
      int k = (int)(e >> 10), r = (int)(e & 1023);
      p.ws[idx] = p.big_src[mi][(size_t)r * 256 + k];
      continue;
    }
    idx -= NBIG;
    if (idx < NI0) {   // [1024][6] -> [6][1024]
      int mi = (int)(idx / 6144);
      size_t e = idx - (size_t)mi * 6144;
      int k = (int)(e >> 10), r = (int)(e & 1023);
      p.ws[O_WT_N_IH0 + idx] = p.ih0_src[mi][(size_t)r * 6 + k];
      continue;
    }
    idx -= NI0;
    if (idx < NATT) {  // [256][256] -> [k][c]
      int mi = (int)(idx / 65536);
      size_t e = idx - (size_t)mi * 65536;
      int k = (int)(e >> 8), c = (int)(e & 255);
      p.ws[O_WT_Q + idx] = p.att_src[mi][(size_t)c * 256 + k];
      continue;
    }
    idx -= NATT;
    if (idx < NCV) {   // Wconv[o][c][dt] -> Wct[dt][c][o], dt<2 only
      int dt = (int)(idx / (512 * 256));
      size_t e = idx - (size_t)dt * 512 * 256;
      int c = (int)(e >> 8), o = (int)(e & 255);
      p.ws[O_WCT + idx] = p.Wconv[(size_t)o * 1536 + (size_t)c * 3 + dt];
      continue;
    }
    idx -= NCV;
    {  // combined biases
      int li = (int)(idx >> 10), jj = (int)(idx & 1023);
      p.ws[O_BC + idx] = p.bih[li][jj] + p.bhh[li][jj];
    }
  }
}

// ---------------- LSTM building blocks ----------------
// acc[g][m] += sum_k hs[mlo+m][k] * Wt[k][g*256 + j]   (Wtj pre-offset by j)
template <int MHT>
DEV void matmul_acc(float (&acc)[4][MHT], const float (*hs)[H_], int mlo,
                    const float* Wtj) {
  for (int k0 = 0; k0 < H_; k0 += 4) {
    float w[4][4];
#pragma unroll
    for (int kk = 0; kk < 4; ++kk) {
      const float* wp = Wtj + (size_t)(k0 + kk) * G_;
      w[kk][0] = wp[0];
      w[kk][1] = wp[256];
      w[kk][2] = wp[512];
      w[kk][3] = wp[768];
    }
#pragma unroll
    for (int m = 0; m < MHT; ++m) {
      const float4 h4 = *reinterpret_cast<const float4*>(&hs[mlo + m][k0]);
#pragma unroll
      for (int g = 0; g < 4; ++g) {
        acc[g][m] = fmaf(w[0][g], h4.x, acc[g][m]);
        acc[g][m] = fmaf(w[1][g], h4.y, acc[g][m]);
        acc[g][m] = fmaf(w[2][g], h4.z, acc[g][m]);
        acc[g][m] = fmaf(w[3][g], h4.w, acc[g][m]);
      }
    }
  }
}

template <int MHT>
DEV void cell_update(float (&acc)[4][MHT], float (&c)[MHT], float (&hn)[MHT]) {
#pragma unroll
  for (int m = 0; m < MHT; ++m) {
    float iv = 1.f / (1.f + __expf(-acc[0][m]));
    float fv = 1.f / (1.f + __expf(-acc[1][m]));
    float gv = tanhf(acc[2][m]);
    float ov = 1.f / (1.f + __expf(-acc[3][m]));
    float cv = fv * c[m] + iv * gv;
    c[m] = cv;
    hn[m] = ov * tanhf(cv);
  }
}

// ---------------- fused ego+nbr 2-layer LSTM encoder ----------------
__global__ __launch_bounds__(512) void encoder_kernel(Par p) {
  __shared__ float h0[MC][H_];
  __shared__ float h1[MC][H_];
  __shared__ float xs[MC][IN_];
  const int tid = threadIdx.x;
  const int j = tid & 255, half = tid >> 8;
  const int mlo = half * MH;
  const int bid = blockIdx.x;
  const bool ego = bid >= NBLK_N;
  const int base = ego ? (bid - NBLK_N) * MC : bid * MC;
  const int nTot = ego ? B_ : NB_;
  const float* Whh0t = p.ws + (ego ? O_WT_E_HH0 : O_WT_N_HH0) + j;
  const float* Wih1t = p.ws + (ego ? O_WT_E_IH1 : O_WT_N_IH1) + j;
  const float* Whh1t = p.ws + (ego ? O_WT_E_HH1 : O_WT_N_HH1) + j;
  const float* Wih0t = p.ws + (ego ? O_WT_E_IH0 : O_WT_N_IH0) + j;
  const float* bc0 = p.ws + O_BC + (ego ? 2048 : 0);
  const float* bc1 = bc0 + 1024;
  float b0j[4], b1j[4];
#pragma unroll
  for (int g = 0; g < 4; ++g) {
    b0j[g] = bc0[g * 256 + j];
    b1j[g] = bc1[g * 256 + j];
  }
  for (int idx = tid; idx < MC * H_; idx += 512) {
    (&h0[0][0])[idx] = 0.f;
    (&h1[0][0])[idx] = 0.f;
  }
  float c0r[MH], c1r[MH];
#pragma unroll
  for (int m = 0; m < MH; ++m) { c0r[m] = 0.f; c1r[m] = 0.f; }
  __syncthreads();

  for (int t = 0; t < T_; ++t) {
    // stage x_t for this block's samples
    if (tid < MC * IN_) {
      int m = tid / IN_, i2 = tid - m * IN_;
      int n = base + m;
      if (n > nTot - 1) n = nTot - 1;  // clamp pad samples (never stored)
      int row = ego ? n * A_ : (n / NN_) * A_ + 1 + (n % NN_);
      xs[m][i2] = p.x[(size_t)row * XROW + t * IN_ + i2];
    }
    __syncthreads();

    // ---- layer 0 ----
    float acc[4][MH];
#pragma unroll
    for (int g = 0; g < 4; ++g)
#pragma unroll
      for (int m = 0; m < MH; ++m) acc[g][m] = b0j[g];
#pragma unroll
    for (int i2 = 0; i2 < IN_; ++i2) {
      const float* wp = Wih0t + (size_t)i2 * G_;
      float w0 = wp[0], w1 = wp[256], w2 = wp[512], w3 = wp[768];
#pragma unroll
      for (int m = 0; m < MH; ++m) {
        float xv = xs[mlo + m][i2];
        acc[0][m] = fmaf(w0, xv, acc[0][m]);
        acc[1][m] = fmaf(w1, xv, acc[1][m]);
        acc[2][m] = fmaf(w2, xv, acc[2][m]);
        acc[3][m] = fmaf(w3, xv, acc[3][m]);
      }
    }
    matmul_acc<MH>(acc, h0, mlo, Whh0t);
    float hn[MH];
    cell_update<MH>(acc, c0r, hn);
    __syncthreads();  // everyone done reading h0
#pragma unroll
    for (int m = 0; m < MH; ++m) h0[mlo + m][j] = hn[m];
    __syncthreads();  // h0_t visible as layer-1 input

    // ---- layer 1 ----
#pragma unroll
    for (int g = 0; g < 4; ++g)
#pragma unroll
      for (int m = 0; m < MH; ++m) acc[g][m] = b1j[g];
    matmul_acc<MH>(acc, h0, mlo, Wih1t);
    matmul_acc<MH>(acc, h1, mlo, Whh1t);
    cell_update<MH>(acc, c1r, hn);
    __syncthreads();  // everyone done reading h1
#pragma unroll
    for (int m = 0; m < MH; ++m) h1[mlo + m][j] = hn[m];
    if (t >= T_ - 2) {  // only t=48,49 ever consumed downstream
      int t2 = t - (T_ - 2);
#pragma unroll
      for (int m = 0; m < MH; ++m) {
        int n = base + mlo + m;
        if (n < nTot) {
          if (!ego)
            p.ws[O_NBR_H1 + ((size_t)t2 * NB_ + n) * H_ + j] = hn[m];
          else
            p.ws[O_COMB + ((size_t)t2 * B_ + n) * 512 + j] = hn[m];
        }
      }
    }
    __syncthreads();
  }
}

// ---------------- attention at t=48,49 (one block per (t2,b)) ----------------
__global__ __launch_bounds__(256) void attn_kernel(Par p) {
  __shared__ float kk[NN_][H_];
  __shared__ float vv[NN_][H_];
  __shared__ float e[H_];
  __shared__ float q[H_];
  __shared__ float att[H_];
  __shared__ float sc[NH_][NN_];
  const int tid = threadIdx.x;
  const int bid = blockIdx.x;
  const int t2 = bid >> 8, b = bid & 255;

  e[tid] = p.ws[O_COMB + ((size_t)t2 * B_ + b) * 512 + tid];
  __syncthreads();
  {  // q = ego @ Wq^T + bq
    float a = p.bq[tid];
    const float* Wq = p.ws + O_WT_Q + tid;
    for (int k0 = 0; k0 < H_; k0 += 4) {
      const float4 e4 = *reinterpret_cast<const float4*>(&e[k0]);
      a = fmaf(Wq[(size_t)k0 * 256], e4.x, a);
      a = fmaf(Wq[(size_t)(k0 + 1) * 256], e4.y, a);
      a = fmaf(Wq[(size_t)(k0 + 2) * 256], e4.z, a);
      a = fmaf(Wq[(size_t)(k0 + 3) * 256], e4.w, a);
    }
    q[tid] = a;
  }
  {  // k,v for 19 neighbors
    float ak[NN_], av[NN_];
#pragma unroll
    for (int n = 0; n < NN_; ++n) { ak[n] = p.bk[tid]; av[n] = p.bv[tid]; }
    const float* Wk = p.ws + O_WT_K + tid;
    const float* Wv = p.ws + O_WT_V + tid;
    const float* hb = p.ws + O_NBR_H1 + ((size_t)t2 * NB_ + (size_t)b * NN_) * H_;
    for (int k0 = 0; k0 < H_; k0 += 4) {
      float wk0 = Wk[(size_t)k0 * 256], wk1 = Wk[(size_t)(k0 + 1) * 256];
      float wk2 = Wk[(size_t)(k0 + 2) * 256], wk3 = Wk[(size_t)(k0 + 3) * 256];
      float wv0 = Wv[(size_t)k0 * 256], wv1 = Wv[(size_t)(k0 + 1) * 256];
      float wv2 = Wv[(size_t)(k0 + 2) * 256], wv3 = Wv[(size_t)(k0 + 3) * 256];
#pragma unroll
      for (int n = 0; n < NN_; ++n) {
        const float4 h4 =
            *reinterpret_cast<const float4*>(hb + (size_t)n * H_ + k0);
        ak[n] = fmaf(wk0, h4.x, ak[n]);
        ak[n] = fmaf(wk1, h4.y, ak[n]);
        ak[n] = fmaf(wk2, h4.z, ak[n]);
        ak[n] = fmaf(wk3, h4.w, ak[n]);
        av[n] = fmaf(wv0, h4.x, av[n]);
        av[n] = fmaf(wv1, h4.y, av[n]);
        av[n] = fmaf(wv2, h4.z, av[n]);
        av[n] = fmaf(wv3, h4.w, av[n]);
      }
    }
#pragma unroll
    for (int n = 0; n < NN_; ++n) { kk[n][tid] = ak[n]; vv[n][tid] = av[n]; }
  }
  __syncthreads();
  if (tid < NH_ * NN_) {  // scores
    int h = tid / NN_, n = tid - h * NN_;
    float s = 0.f;
#pragma unroll
    for (int d = 0; d < 32; ++d) s = fmaf(q[h * 32 + d], kk[n][h * 32 + d], s);
    sc[h][n] = s * 0.17677669529663687f;  // 1/sqrt(32)
  }
  __syncthreads();
  if (tid < NH_) {  // softmax over 19 neighbors
    float mx = sc[tid][0];
#pragma unroll
    for (int n = 1; n < NN_; ++n) mx = fmaxf(mx, sc[tid][n]);
    float den = 0.f, w[NN_];
#pragma unroll
    for (int n = 0; n < NN_; ++n) {
      w[n] = __expf(sc[tid][n] - mx);
      den += w[n];
    }
    float r = 1.f / den;
#pragma unroll
    for (int n = 0; n < NN_; ++n) sc[tid][n] = w[n] * r;
  }
  __syncthreads();
  {  // att = sum_n w*v
    int h = tid >> 5;
    float a = 0.f;
#pragma unroll
    for (int n = 0; n < NN_; ++n) a = fmaf(sc[h][n], vv[n][tid], a);
    att[tid] = a;
  }
  __syncthreads();
  {  // out-projection -> comb[...,256:512]
    float a = p.bao[tid];
    const float* Wao = p.ws + O_WT_AO + tid;
    for (int k0 = 0; k0 < H_; k0 += 4) {
      const float4 a4 = *reinterpret_cast<const float4*>(&att[k0]);
      a = fmaf(Wao[(size_t)k0 * 256], a4.x, a);
      a = fmaf(Wao[(size_t)(k0 + 1) * 256], a4.y, a);
      a = fmaf(Wao[(size_t)(k0 + 2) * 256], a4.z, a);
      a = fmaf(Wao[(size_t)(k0 + 3) * 256], a4.w, a);
    }
    p.ws[O_COMB + ((size_t)t2 * B_ + b) * 512 + 256 + tid] = a;
  }
}

// -------- conv (only output t=49 is live) + decoder layer-0 x-part --------
__global__ __launch_bounds__(256) void conv_kernel(Par p) {
  __shared__ float cl[2][512];
  __shared__ float tf[H_];
  const int b = blockIdx.x, tid = threadIdx.x;
  for (int idx = tid; idx < 1024; idx += 256) {
    int t2 = idx >> 9, c = idx & 511;
    cl[t2][c] = p.ws[O_COMB + ((size_t)t2 * B_ + b) * 512 + c];
  }
  __syncthreads();
  {  // tf[49][b][o]: kernel taps 0 (t=48) and 1 (t=49); tap 2 hits zero pad
    float a = p.bconv[tid];
    const float* W0 = p.ws + O_WCT + tid;
    const float* W1 = W0 + 512 * 256;
    for (int c = 0; c < 512; ++c) {
      a = fmaf(cl[0][c], W0[(size_t)c * 256], a);
      a = fmaf(cl[1][c], W1[(size_t)c * 256], a);
    }
    tf[tid] = a;
  }
  __syncthreads();
  {  // pre0[b][r] = bc_d0[r] + tf . Wt_d_ih0[:,r]  (constant across all 60 steps)
    float accp[4];
    const float* bcd0 = p.ws + O_BC + 4096;
#pragma unroll
    for (int g = 0; g < 4; ++g) accp[g] = bcd0[g * 256 + tid];
    const float* Wt = p.ws + O_WT_D_IH0 + tid;
    for (int k0 = 0; k0 < H_; k0 += 4) {
      const float4 t4 = *reinterpret_cast<const float4*>(&tf[k0]);
      float tv[4] = {t4.x, t4.y, t4.z, t4.w};
#pragma unroll
      for (int kq = 0; kq < 4; ++kq) {
        const float* wp = Wt + (size_t)(k0 + kq) * G_;
        accp[0] = fmaf(wp[0], tv[kq], accp[0]);
        accp[1] = fmaf(wp[256], tv[kq], accp[1]);
        accp[2] = fmaf(wp[512], tv[kq], accp[2]);
        accp[3] = fmaf(wp[768], tv[kq], accp[3]);
      }
    }
#pragma unroll
    for (int g = 0; g < 4; ++g)
      p.ws[O_PRE0 + (size_t)b * G_ + g * 256 + tid] = accp[g];
  }
}

// ---------------- decoder: 2-layer LSTM, 60 steps, + output head ----------------
__global__ __launch_bounds__(512) void decoder_kernel(Par p) {
  __shared__ float h0[DM][H_];
  __shared__ float h1[DM][H_];
  __shared__ float pre0s[DM][G_];
  __shared__ float red[8][2];
  const int tid = threadIdx.x;
  const int j = tid & 255, half = tid >> 8;
  const int mlo = half * DMH;
  const int base = blockIdx.x * DM;
  for (int idx = tid; idx < DM * H_; idx += 512) {
    (&h0[0][0])[idx] = 0.f;
    (&h1[0][0])[idx] = 0.f;
  }
  for (int idx = tid; idx < DM * G_; idx += 512)
    (&pre0s[0][0])[idx] = p.ws[O_PRE0 + (size_t)base * G_ + idx];
  float c0r[DMH] = {0.f, 0.f}, c1r[DMH] = {0.f, 0.f};
  const float* Whh0t = p.ws + O_WT_D_HH0 + j;
  const float* Wih1t = p.ws + O_WT_D_IH1 + j;
  const float* Whh1t = p.ws + O_WT_D_HH1 + j;
  const float* bc1 = p.ws + O_BC + 5120;
  float b1j[4];
#pragma unroll
  for (int g = 0; g < 4; ++g) b1j[g] = bc1[g * 256 + j];
  __syncthreads();

  for (int t = 0; t < DT_; ++t) {
    float acc[4][DMH];
#pragma unroll
    for (int g = 0; g < 4; ++g)
#pragma unroll
      for (int m = 0; m < DMH; ++m) acc[g][m] = pre0s[mlo + m][g * 256 + j];
    matmul_acc<DMH>(acc, h0, mlo, Whh0t);
    float hn[DMH];
    cell_update<DMH>(acc, c0r, hn);
    __syncthreads();
#pragma unroll
    for (int m = 0; m < DMH; ++m) h0[mlo + m][j] = hn[m];
    __syncthreads();
#pragma unroll
    for (int g = 0; g < 4; ++g)
#pragma unroll
      for (int m = 0; m < DMH; ++m) acc[g][m] = b1j[g];
    matmul_acc<DMH>(acc, h0, mlo, Wih1t);
    matmul_acc<DMH>(acc, h1, mlo, Whh1t);
    cell_update<DMH>(acc, c1r, hn);
    __syncthreads();
#pragma unroll
    for (int m = 0; m < DMH; ++m) h1[mlo + m][j] = hn[m];
    __syncthreads();
    {  // pred[m][0:2] = h1[m] @ Wout^T + bout ; wave-parallel reduction
      const int w = tid >> 6, lane = tid & 63;
      const int m = w >> 1;
      const int k2 = (((w & 1) << 6) | lane) << 1;
      float ha = h1[m][k2], hb = h1[m][k2 + 1];
      float p0 = ha * p.Wout[k2] + hb * p.Wout[k2 + 1];
      float p1 = ha * p.Wout[256 + k2] + hb * p.Wout[256 + k2 + 1];
#pragma unroll
      for (int off = 32; off > 0; off >>= 1) {
        p0 += __shfl_xor(p0, off);
        p1 += __shfl_xor(p1, off);
      }
      if (lane == 0) { red[w][0] = p0; red[w][1] = p1; }
    }
    __syncthreads();
    if (tid < 8) {
      int mm = tid >> 1, pp = tid & 1;
      float v = red[2 * mm][pp] + red[2 * mm + 1][pp] + p.bout[pp];
      p.out[((size_t)(base + mm) * DT_ + t) * 2 + pp] = v;
    }
    __syncthreads();
  }
}

// ---------------- host launcher ----------------
extern "C" void kernel_launch(void* const* d_in, const int* in_sizes, int n_in,
                              void* d_out, int out_size, void* d_ws,
                              size_t ws_size, hipStream_t stream) {
  (void)in_sizes; (void)n_in; (void)out_size; (void)ws_size;
  auto F = [&](int i) { return (const float*)d_in[i]; };
  Par p{};
  p.x = F(0);
  // transposed-weight sources, in ws offset order
  p.big_src[0] = F(10);  // nbr_Whh0
  p.big_src[1] = F(13);  // nbr_Wih1
  p.big_src[2] = F(14);  // nbr_Whh1
  p.big_src[3] = F(2);   // ego_Whh0
  p.big_src[4] = F(5);   // ego_Wih1
  p.big_src[5] = F(6);   // ego_Whh1
  p.big_src[6] = F(18);  // dec_Whh0
  p.big_src[7] = F(21);  // dec_Wih1
  p.big_src[8] = F(22);  // dec_Whh1
  p.big_src[9] = F(17);  // dec_Wih0
  p.ih0_src[0] = F(9);   // nbr_Wih0
  p.ih0_src[1] = F(1);   // ego_Wih0
  p.att_src[0] = F(25); p.att_src[1] = F(26);
  p.att_src[2] = F(27); p.att_src[3] = F(28);
  p.Wconv = F(33);
  p.bih[0] = F(11); p.bhh[0] = F(12);  // nbr l0
  p.bih[1] = F(15); p.bhh[1] = F(16);  // nbr l1
  p.bih[2] = F(3);  p.bhh[2] = F(4);   // ego l0
  p.bih[3] = F(7);  p.bhh[3] = F(8);   // ego l1
  p.bih[4] = F(19); p.bhh[4] = F(20);  // dec l0
  p.bih[5] = F(23); p.bhh[5] = F(24);  // dec l1
  p.bq = F(29); p.bk = F(30); p.bv = F(31); p.bao = F(32);
  p.bconv = F(34); p.Wout = F(35); p.bout = F(36);
  p.ws = (float*)d_ws;
  p.out = (float*)d_out;

  hipLaunchKernelGGL(prep_kernel, dim3(1024), dim3(256), 0, stream, p);
  hipLaunchKernelGGL(encoder_kernel, dim3(NBLK_ENC), dim3(512), 0, stream, p);
  hipLaunchKernelGGL(attn_kernel, dim3(512), dim3(256), 0, stream, p);
  hipLaunchKernelGGL(conv_kernel, dim3(B_), dim3(256), 0, stream, p);
  hipLaunchKernelGGL(decoder_kernel, dim3(NBLK_DEC), dim3(512), 0, stream, p);
}

// Round 3
// 8206.899 us; speedup vs baseline: 1.2166x; 1.2166x over previous
//
#include <hip/hip_runtime.h>

#define DEV __device__ __forceinline__

typedef _Float16 f16x8 __attribute__((ext_vector_type(8)));
typedef float f32x4 __attribute__((ext_vector_type(4)));

// ---- problem dims ----
constexpr int B_ = 256, A_ = 20, T_ = 50, IN_ = 6;
constexpr int H_ = 256, G_ = 1024, NH_ = 8, DT_ = 60;
constexpr int NN_ = 19;
constexpr int NB_ = B_ * NN_;   // 4864
constexpr int XROW = T_ * IN_;  // 300

// encoder: M=32 per block (2 MFMA M-tiles), 160 blocks (152 nbr + 8 ego)
constexpr int NBLK_ENC = 160;
constexpr int EGO_B0 = 152;     // tiles 304.. are ego
// decoder: M=16 per block, 16 blocks
constexpr int NBLK_DEC = 16;

// ---- ws byte offsets ----
// B-fragment layout for W^T[k][j] (j=gate*256+col): frag[((jt*KT+kt)*64+l)*8+e]
//   = (fp16) W[n*256+k], n=jt*16+(l&15), k=kt*32+(l>>4)*8+e   (KT=8)
constexpr size_t FB = 64ull * 8 * 64 * 8 * 2;  // 512KB per 1024x256 matrix
constexpr size_t FS = 64ull * 64 * 8 * 2;      // 64KB per 1024x6 (K padded to 32)
constexpr size_t O_F_NHH0 = 0;
constexpr size_t O_F_NIH1 = O_F_NHH0 + FB;
constexpr size_t O_F_NHH1 = O_F_NIH1 + FB;
constexpr size_t O_F_EHH0 = O_F_NHH1 + FB;
constexpr size_t O_F_EIH1 = O_F_EHH0 + FB;
constexpr size_t O_F_EHH1 = O_F_EIH1 + FB;
constexpr size_t O_F_DHH0 = O_F_EHH1 + FB;
constexpr size_t O_F_DIH1 = O_F_DHH0 + FB;
constexpr size_t O_F_DHH1 = O_F_DIH1 + FB;
constexpr size_t O_F_NIH0 = O_F_DHH1 + FB;
constexpr size_t O_F_EIH0 = O_F_NIH0 + FS;
constexpr size_t B_BC    = O_F_EIH0 + FS;            // 6*1024 fp32 (n0,n1,e0,e1,d0,d1)
constexpr size_t B_ATT   = B_BC + 6 * 1024 * 4;      // 4 x [k][256] fp32
constexpr size_t B_WCT   = B_ATT + 4 * 65536 * 4;    // [2][512][256] fp32
constexpr size_t B_DIH0T = B_WCT + 2 * 512 * 256 * 4;// [k][1024] fp32
constexpr size_t B_NBRH1 = B_DIH0T + 256 * 1024 * 4; // [2][4864][256] fp32
constexpr size_t B_COMB  = B_NBRH1 + 2ull * NB_ * H_ * 4;  // [2][256][512] fp32
constexpr size_t B_PRE0  = B_COMB + 2ull * B_ * 512 * 4;   // [256][1024] fp32

struct Par {
  const float* x;
  const float* big_src[10];  // 9 recurrent 1024x256 mats (frag order) + dec_Wih0
  const float* ih0_src[2];   // nbr_Wih0, ego_Wih0 (1024x6)
  const float* att_src[4];   // Wq, Wk, Wv, Wao
  const float* Wconv;
  const float* bih[6];       // n0,n1,e0,e1,d0,d1
  const float* bhh[6];
  const float *bq, *bk, *bv, *bao, *bconv, *Wout, *bout;
  float* ws;
  float* out;
};

// ---------------- prep: fragment packing + transposes + bias sums ----------------
__global__ void prep_kernel(Par p) {
  char* wsb = (char*)p.ws;
  const size_t NBIG = 9ull * 262144;   // fp16 elems
  const size_t NIH0 = 2ull * 32768;    // fp16 elems
  const size_t NBC  = 6144;
  const size_t NATT = 4ull * 65536;
  const size_t NWCT = 2ull * 512 * 256;
  const size_t NDIH = 256ull * 1024;
  const size_t total = NBIG + NIH0 + NBC + NATT + NWCT + NDIH;
  for (size_t i = (size_t)blockIdx.x * blockDim.x + threadIdx.x; i < total;
       i += (size_t)gridDim.x * blockDim.x) {
    size_t idx = i;
    if (idx < NBIG) {
      int mi = (int)(idx / 262144);
      size_t f = idx - (size_t)mi * 262144;
      int e = (int)(f & 7), l = (int)((f >> 3) & 63);
      int kt = (int)((f >> 9) & 7), jt = (int)(f >> 12);
      int n = jt * 16 + (l & 15), k = kt * 32 + (l >> 4) * 8 + e;
      ((_Float16*)(wsb + O_F_NHH0))[idx] =
          (_Float16)p.big_src[mi][(size_t)n * 256 + k];
      continue;
    }
    idx -= NBIG;
    if (idx < NIH0) {
      int mi = (int)(idx >> 15);
      size_t f = idx & 32767;
      int e = (int)(f & 7), l = (int)((f >> 3) & 63), jt = (int)(f >> 9);
      int n = jt * 16 + (l & 15), k = (l >> 4) * 8 + e;
      ((_Float16*)(wsb + O_F_NIH0))[idx] =
          (_Float16)(k < 6 ? p.ih0_src[mi][(size_t)n * 6 + k] : 0.f);
      continue;
    }
    idx -= NIH0;
    if (idx < NBC) {
      int li = (int)(idx >> 10), jj = (int)(idx & 1023);
      ((float*)(wsb + B_BC))[idx] = p.bih[li][jj] + p.bhh[li][jj];
      continue;
    }
    idx -= NBC;
    if (idx < NATT) {
      int mi = (int)(idx >> 16);
      size_t f = idx & 65535;
      int k = (int)(f >> 8), c = (int)(f & 255);
      ((float*)(wsb + B_ATT))[idx] = p.att_src[mi][(size_t)c * 256 + k];
      continue;
    }
    idx -= NATT;
    if (idx < NWCT) {  // Wconv[o][c][dt] -> [dt][c][o], dt<2
      int dt = (int)(idx / (512 * 256));
      size_t f = idx - (size_t)dt * 512 * 256;
      int c = (int)(f >> 8), o = (int)(f & 255);
      ((float*)(wsb + B_WCT))[idx] = p.Wconv[(size_t)o * 1536 + (size_t)c * 3 + dt];
      continue;
    }
    idx -= NWCT;
    {  // dec_Wih0 [1024][256] -> [k][1024]
      int k = (int)(idx >> 10), j = (int)(idx & 1023);
      ((float*)(wsb + B_DIH0T))[idx] = p.big_src[9][(size_t)j * 256 + k];
    }
  }
}

// ---------------- MFMA LSTM building blocks ----------------
DEV float fsig(float x) { return 1.f / (1.f + __expf(-x)); }
DEV float ftanh(float x) { return 1.f - 2.f / (__expf(2.f * x) + 1.f); }

// acc[mt][g][t2] += H[mt-tile rows][k] @ Wfrag ; split-h: hi+lo MFMAs
template <int MT>
DEV void mm_frag(f32x4 (&acc)[MT][4][2], const _Float16* Hhi,
                 const _Float16* Hlo, const _Float16* __restrict__ WB,
                 int w, int l) {
  const int m15 = l & 15, khi = (l >> 4) * 8;
#pragma unroll
  for (int kt = 0; kt < 8; ++kt) {
    f16x8 ah[MT], al[MT];
#pragma unroll
    for (int mt = 0; mt < MT; ++mt) {
      int off = (mt * 16 + m15) * 264 + kt * 32 + khi;
      ah[mt] = *(const f16x8*)(Hhi + off);
      al[mt] = *(const f16x8*)(Hlo + off);
    }
#pragma unroll
    for (int g = 0; g < 4; ++g)
#pragma unroll
      for (int t2 = 0; t2 < 2; ++t2) {
        int jt = g * 16 + w * 2 + t2;
        f16x8 b = *(const f16x8*)(WB + ((size_t)(jt * 8 + kt) * 64 + l) * 8);
#pragma unroll
        for (int mt = 0; mt < MT; ++mt) {
          acc[mt][g][t2] =
              __builtin_amdgcn_mfma_f32_16x16x32_f16(ah[mt], b, acc[mt][g][t2], 0, 0, 0);
          acc[mt][g][t2] =
              __builtin_amdgcn_mfma_f32_16x16x32_f16(al[mt], b, acc[mt][g][t2], 0, 0, 0);
        }
      }
  }
}

template <int MT>
DEV void acc_init(f32x4 (&acc)[MT][4][2], const float (&b)[4][2]) {
#pragma unroll
  for (int mt = 0; mt < MT; ++mt)
#pragma unroll
    for (int g = 0; g < 4; ++g)
#pragma unroll
      for (int t2 = 0; t2 < 2; ++t2) {
        f32x4 v = {b[g][t2], b[g][t2], b[g][t2], b[g][t2]};
        acc[mt][g][t2] = v;
      }
}

// LSTM cell update; writes new h (hi/lo fp16) into LDS at D-layout positions.
// hout gets fp32 h values (for optional global stores).
template <int MT>
DEV void cell_upd(f32x4 (&acc)[MT][4][2], f32x4 (&c)[MT][2], _Float16* Hhi,
                  _Float16* Hlo, int w, int l, float (&hout)[MT][2][4]) {
  const int rbase = (l >> 4) * 4, m15 = l & 15;
#pragma unroll
  for (int mt = 0; mt < MT; ++mt)
#pragma unroll
    for (int t2 = 0; t2 < 2; ++t2)
#pragma unroll
      for (int r = 0; r < 4; ++r) {
        float iv = fsig(acc[mt][0][t2][r]);
        float fv = fsig(acc[mt][1][t2][r]);
        float gv = ftanh(acc[mt][2][t2][r]);
        float ov = fsig(acc[mt][3][t2][r]);
        float cv = fv * c[mt][t2][r] + iv * gv;
        c[mt][t2][r] = cv;
        float hv = ov * ftanh(cv);
        hout[mt][t2][r] = hv;
        int m = mt * 16 + rbase + r, col = w * 32 + t2 * 16 + m15;
        _Float16 hi = (_Float16)hv;
        Hhi[m * 264 + col] = hi;
        Hlo[m * 264 + col] = (_Float16)(hv - (float)hi);
      }
}

// ---------------- encoder: fused ego+nbr 2-layer LSTM (MFMA) ----------------
__global__ __launch_bounds__(512, 2) void encoder_kernel(Par p) {
  // [layer][buf][hi/lo][m 0..31][k pad 264]
  __shared__ _Float16 Hs[2][2][2][32][264];
  __shared__ _Float16 XF[2][2][512];  // [buf][mt][lane*8] A-frag of x (K pad 32)
  const int tid = threadIdx.x, w = tid >> 6, l = tid & 63;
  const int bid = blockIdx.x;
  const bool ego = bid >= EGO_B0;
  char* wsb = (char*)p.ws;
  const _Float16* WB_hh0 = (const _Float16*)(wsb + (ego ? O_F_EHH0 : O_F_NHH0));
  const _Float16* WB_ih1 = (const _Float16*)(wsb + (ego ? O_F_EIH1 : O_F_NIH1));
  const _Float16* WB_hh1 = (const _Float16*)(wsb + (ego ? O_F_EHH1 : O_F_NHH1));
  const _Float16* WB_ih0 = (const _Float16*)(wsb + (ego ? O_F_EIH0 : O_F_NIH0));

  for (int i = tid; i < 2 * 2 * 2 * 32 * 264; i += 512)
    ((_Float16*)Hs)[i] = (_Float16)0.f;
  for (int i = tid; i < 2 * 2 * 512; i += 512) ((_Float16*)XF)[i] = (_Float16)0.f;

  // biases
  const float* bcb = (const float*)(wsb + B_BC) + (ego ? 2048 : 0);
  float b0v[4][2], b1v[4][2];
#pragma unroll
  for (int g = 0; g < 4; ++g)
#pragma unroll
    for (int t2 = 0; t2 < 2; ++t2) {
      int j = g * 256 + w * 32 + t2 * 16 + (l & 15);
      b0v[g][t2] = bcb[j];
      b1v[g][t2] = bcb[1024 + j];
    }

  // x staging assignment (thread tid<192 -> (m32, kx))
  const int m32 = tid / 6, kx = tid - m32 * 6;
  const float* xp = nullptr;
  int xslot = 0;
  if (tid < 192) {
    int row;
    if (!ego) {
      int n = bid * 32 + m32;
      int q = n / 19;
      row = q * 20 + 1 + (n - q * 19);
    } else {
      int b = (bid - EGO_B0) * 32 + m32;
      row = b * 20;
    }
    xp = p.x + (size_t)row * XROW + kx;
    xslot = (m32 >> 4) * 512 + (m32 & 15) * 8 + kx;
  }

  f32x4 c0[2][2] = {}, c1[2][2] = {};
  float h0v[2][2][4], h1v[2][2][4];
  __syncthreads();
  if (tid < 192) ((_Float16*)XF[0])[xslot] = (_Float16)xp[0];
  __syncthreads();

  int pb = 0;
  for (int t = 0; t < T_; ++t) {
    // ---- layer 0: x@Wih0 + h0@Whh0 ----
    f32x4 acc[2][4][2];
    acc_init<2>(acc, b0v);
    {
      f16x8 a0 = *(const f16x8*)(&XF[pb][0][l * 8]);
      f16x8 a1 = *(const f16x8*)(&XF[pb][1][l * 8]);
#pragma unroll
      for (int g = 0; g < 4; ++g)
#pragma unroll
        for (int t2 = 0; t2 < 2; ++t2) {
          int jt = g * 16 + w * 2 + t2;
          f16x8 b = *(const f16x8*)(WB_ih0 + ((size_t)jt * 64 + l) * 8);
          acc[0][g][t2] = __builtin_amdgcn_mfma_f32_16x16x32_f16(a0, b, acc[0][g][t2], 0, 0, 0);
          acc[1][g][t2] = __builtin_amdgcn_mfma_f32_16x16x32_f16(a1, b, acc[1][g][t2], 0, 0, 0);
        }
    }
    mm_frag<2>(acc, &Hs[0][pb][0][0][0], &Hs[0][pb][1][0][0], WB_hh0, w, l);
    cell_upd<2>(acc, c0, &Hs[0][pb ^ 1][0][0][0], &Hs[0][pb ^ 1][1][0][0], w, l, h0v);
    __syncthreads();  // h0_new visible

    // ---- layer 1: h0_new@Wih1 + h1_old@Whh1 ----
    acc_init<2>(acc, b1v);
    mm_frag<2>(acc, &Hs[0][pb ^ 1][0][0][0], &Hs[0][pb ^ 1][1][0][0], WB_ih1, w, l);
    mm_frag<2>(acc, &Hs[1][pb][0][0][0], &Hs[1][pb][1][0][0], WB_hh1, w, l);
    if (t < T_ - 1 && tid < 192)
      ((_Float16*)XF[pb ^ 1])[xslot] = (_Float16)xp[(t + 1) * IN_];
    cell_upd<2>(acc, c1, &Hs[1][pb ^ 1][0][0][0], &Hs[1][pb ^ 1][1][0][0], w, l, h1v);

    if (t >= T_ - 2) {  // only t=48,49 consumed downstream
      int tg = t - (T_ - 2);
      const int rbase = (l >> 4) * 4, m15 = l & 15;
#pragma unroll
      for (int mt = 0; mt < 2; ++mt)
#pragma unroll
        for (int t2 = 0; t2 < 2; ++t2)
#pragma unroll
          for (int r = 0; r < 4; ++r) {
            int mloc = mt * 16 + rbase + r, col = w * 32 + t2 * 16 + m15;
            if (!ego) {
              int n = bid * 32 + mloc;
              ((float*)(wsb + B_NBRH1))[((size_t)tg * NB_ + n) * H_ + col] =
                  h1v[mt][t2][r];
            } else {
              int b = (bid - EGO_B0) * 32 + mloc;
              ((float*)(wsb + B_COMB))[((size_t)tg * B_ + b) * 512 + col] =
                  h1v[mt][t2][r];
            }
          }
    }
    __syncthreads();  // h1_new + x_{t+1} visible
    pb ^= 1;
  }
}

// ---------------- attention at t=48,49 (one block per (t2,b)) ----------------
__global__ __launch_bounds__(256) void attn_kernel(Par p) {
  __shared__ float kk[NN_][H_];
  __shared__ float vv[NN_][H_];
  __shared__ float e[H_];
  __shared__ float q[H_];
  __shared__ float att[H_];
  __shared__ float sc[NH_][NN_];
  const int tid = threadIdx.x;
  const int bid = blockIdx.x;
  const int t2 = bid >> 8, b = bid & 255;
  char* wsb = (char*)p.ws;
  const float* attw = (const float*)(wsb + B_ATT);
  float* comb = (float*)(wsb + B_COMB);

  e[tid] = comb[((size_t)t2 * B_ + b) * 512 + tid];
  __syncthreads();
  {  // q = ego @ Wq^T + bq
    float a = p.bq[tid];
    const float* Wq = attw + tid;
    for (int k0 = 0; k0 < H_; k0 += 4) {
      const float4 e4 = *reinterpret_cast<const float4*>(&e[k0]);
      a = fmaf(Wq[(size_t)k0 * 256], e4.x, a);
      a = fmaf(Wq[(size_t)(k0 + 1) * 256], e4.y, a);
      a = fmaf(Wq[(size_t)(k0 + 2) * 256], e4.z, a);
      a = fmaf(Wq[(size_t)(k0 + 3) * 256], e4.w, a);
    }
    q[tid] = a;
  }
  {  // k,v for 19 neighbors
    float ak[NN_], av[NN_];
#pragma unroll
    for (int n = 0; n < NN_; ++n) { ak[n] = p.bk[tid]; av[n] = p.bv[tid]; }
    const float* Wk = attw + 65536 + tid;
    const float* Wv = attw + 2 * 65536 + tid;
    const float* hb = (const float*)(wsb + B_NBRH1) +
                      ((size_t)t2 * NB_ + (size_t)b * NN_) * H_;
    for (int k0 = 0; k0 < H_; k0 += 4) {
      float wk0 = Wk[(size_t)k0 * 256], wk1 = Wk[(size_t)(k0 + 1) * 256];
      float wk2 = Wk[(size_t)(k0 + 2) * 256], wk3 = Wk[(size_t)(k0 + 3) * 256];
      float wv0 = Wv[(size_t)k0 * 256], wv1 = Wv[(size_t)(k0 + 1) * 256];
      float wv2 = Wv[(size_t)(k0 + 2) * 256], wv3 = Wv[(size_t)(k0 + 3) * 256];
#pragma unroll
      for (int n = 0; n < NN_; ++n) {
        const float4 h4 =
            *reinterpret_cast<const float4*>(hb + (size_t)n * H_ + k0);
        ak[n] = fmaf(wk0, h4.x, ak[n]);
        ak[n] = fmaf(wk1, h4.y, ak[n]);
        ak[n] = fmaf(wk2, h4.z, ak[n]);
        ak[n] = fmaf(wk3, h4.w, ak[n]);
        av[n] = fmaf(wv0, h4.x, av[n]);
        av[n] = fmaf(wv1, h4.y, av[n]);
        av[n] = fmaf(wv2, h4.z, av[n]);
        av[n] = fmaf(wv3, h4.w, av[n]);
      }
    }
#pragma unroll
    for (int n = 0; n < NN_; ++n) { kk[n][tid] = ak[n]; vv[n][tid] = av[n]; }
  }
  __syncthreads();
  if (tid < NH_ * NN_) {  // scores
    int h = tid / NN_, n = tid - h * NN_;
    float s = 0.f;
#pragma unroll
    for (int d = 0; d < 32; ++d) s = fmaf(q[h * 32 + d], kk[n][h * 32 + d], s);
    sc[h][n] = s * 0.17677669529663687f;
  }
  __syncthreads();
  if (tid < NH_) {  // softmax over neighbors
    float mx = sc[tid][0];
#pragma unroll
    for (int n = 1; n < NN_; ++n) mx = fmaxf(mx, sc[tid][n]);
    float den = 0.f, wn[NN_];
#pragma unroll
    for (int n = 0; n < NN_; ++n) {
      wn[n] = __expf(sc[tid][n] - mx);
      den += wn[n];
    }
    float r = 1.f / den;
#pragma unroll
    for (int n = 0; n < NN_; ++n) sc[tid][n] = wn[n] * r;
  }
  __syncthreads();
  {  // att = sum_n w*v
    int h = tid >> 5;
    float a = 0.f;
#pragma unroll
    for (int n = 0; n < NN_; ++n) a = fmaf(sc[h][n], vv[n][tid], a);
    att[tid] = a;
  }
  __syncthreads();
  {  // out-projection
    float a = p.bao[tid];
    const float* Wao = attw + 3 * 65536 + tid;
    for (int k0 = 0; k0 < H_; k0 += 4) {
      const float4 a4 = *reinterpret_cast<const float4*>(&att[k0]);
      a = fmaf(Wao[(size_t)k0 * 256], a4.x, a);
      a = fmaf(Wao[(size_t)(k0 + 1) * 256], a4.y, a);
      a = fmaf(Wao[(size_t)(k0 + 2) * 256], a4.z, a);
      a = fmaf(Wao[(size_t)(k0 + 3) * 256], a4.w, a);
    }
    comb[((size_t)t2 * B_ + b) * 512 + 256 + tid] = a;
  }
}

// -------- conv (only t=49 output live) + decoder layer-0 x-part --------
__global__ __launch_bounds__(256) void conv_kernel(Par p) {
  __shared__ float cl[2][512];
  __shared__ float tf[H_];
  const int b = blockIdx.x, tid = threadIdx.x;
  char* wsb = (char*)p.ws;
  const float* comb = (const float*)(wsb + B_COMB);
  for (int idx = tid; idx < 1024; idx += 256) {
    int t2 = idx >> 9, c = idx & 511;
    cl[t2][c] = comb[((size_t)t2 * B_ + b) * 512 + c];
  }
  __syncthreads();
  {  // conv taps 0 (t=48), 1 (t=49); tap 2 hits zero pad
    float a = p.bconv[tid];
    const float* W0 = (const float*)(wsb + B_WCT) + tid;
    const float* W1 = W0 + 512 * 256;
    for (int c = 0; c < 512; ++c) {
      a = fmaf(cl[0][c], W0[(size_t)c * 256], a);
      a = fmaf(cl[1][c], W1[(size_t)c * 256], a);
    }
    tf[tid] = a;
  }
  __syncthreads();
  {  // pre0[b][j] = bc_d0[j] + tf . Wt_d_ih0[:,j]
    float accp[4];
    const float* bcd0 = (const float*)(wsb + B_BC) + 4096;
#pragma unroll
    for (int g = 0; g < 4; ++g) accp[g] = bcd0[g * 256 + tid];
    const float* Wt = (const float*)(wsb + B_DIH0T) + tid;
    for (int k0 = 0; k0 < H_; k0 += 4) {
      const float4 t4 = *reinterpret_cast<const float4*>(&tf[k0]);
      float tv[4] = {t4.x, t4.y, t4.z, t4.w};
#pragma unroll
      for (int kq = 0; kq < 4; ++kq) {
        const float* wp = Wt + (size_t)(k0 + kq) * G_;
        accp[0] = fmaf(wp[0], tv[kq], accp[0]);
        accp[1] = fmaf(wp[256], tv[kq], accp[1]);
        accp[2] = fmaf(wp[512], tv[kq], accp[2]);
        accp[3] = fmaf(wp[768], tv[kq], accp[3]);
      }
    }
    float* pre0 = (float*)(wsb + B_PRE0);
#pragma unroll
    for (int g = 0; g < 4; ++g) pre0[(size_t)b * G_ + g * 256 + tid] = accp[g];
  }
}

// ---------------- decoder: 2-layer LSTM, 60 steps (MFMA) + head ----------------
__global__ __launch_bounds__(512, 2) void decoder_kernel(Par p) {
  __shared__ _Float16 Hs[2][2][2][16][264];
  const int tid = threadIdx.x, w = tid >> 6, l = tid & 63;
  const int bid = blockIdx.x;
  char* wsb = (char*)p.ws;
  const _Float16* WB_hh0 = (const _Float16*)(wsb + O_F_DHH0);
  const _Float16* WB_ih1 = (const _Float16*)(wsb + O_F_DIH1);
  const _Float16* WB_hh1 = (const _Float16*)(wsb + O_F_DHH1);

  for (int i = tid; i < 2 * 2 * 2 * 16 * 264; i += 512)
    ((_Float16*)Hs)[i] = (_Float16)0.f;

  const float* bcd1 = (const float*)(wsb + B_BC) + 5120;
  float b1v[4][2];
  f32x4 pre[1][4][2];
  {
    const float* pre0 = (const float*)(wsb + B_PRE0);
    const int rbase = (l >> 4) * 4, m15 = l & 15;
#pragma unroll
    for (int g = 0; g < 4; ++g)
#pragma unroll
      for (int t2 = 0; t2 < 2; ++t2) {
        int j = g * 256 + w * 32 + t2 * 16 + m15;
        b1v[g][t2] = bcd1[j];
#pragma unroll
        for (int r = 0; r < 4; ++r)
          pre[0][g][t2][r] = pre0[(size_t)(bid * 16 + rbase + r) * G_ + j];
      }
  }
  // output head constants: thread -> (m, pp, kchunk)
  const int hm = tid >> 5, hpp = (tid >> 4) & 1, hkc = tid & 15;
  float wr[16], bo;
  {
#pragma unroll
    for (int e2 = 0; e2 < 16; ++e2) wr[e2] = p.Wout[hpp * 256 + hkc * 16 + e2];
    bo = p.bout[hpp];
  }

  f32x4 c0[1][2] = {}, c1[1][2] = {};
  float hdum[1][2][4];
  __syncthreads();

  int pb = 0;
  for (int t = 0; t < DT_; ++t) {
    f32x4 acc[1][4][2];
#pragma unroll
    for (int g = 0; g < 4; ++g)
#pragma unroll
      for (int t2 = 0; t2 < 2; ++t2) acc[0][g][t2] = pre[0][g][t2];
    mm_frag<1>(acc, &Hs[0][pb][0][0][0], &Hs[0][pb][1][0][0], WB_hh0, w, l);
    cell_upd<1>(acc, c0, &Hs[0][pb ^ 1][0][0][0], &Hs[0][pb ^ 1][1][0][0], w, l, hdum);
    __syncthreads();

    acc_init<1>(acc, b1v);
    mm_frag<1>(acc, &Hs[0][pb ^ 1][0][0][0], &Hs[0][pb ^ 1][1][0][0], WB_ih1, w, l);
    mm_frag<1>(acc, &Hs[1][pb][0][0][0], &Hs[1][pb][1][0][0], WB_hh1, w, l);
    cell_upd<1>(acc, c1, &Hs[1][pb ^ 1][0][0][0], &Hs[1][pb ^ 1][1][0][0], w, l, hdum);
    __syncthreads();

    {  // head: pred[m][pp] = (h1hi+h1lo) . Wout[pp] + bout[pp]
      const _Float16* h1h = &Hs[1][pb ^ 1][0][hm][hkc * 16];
      const _Float16* h1l = &Hs[1][pb ^ 1][1][hm][hkc * 16];
      f16x8 a0 = *(const f16x8*)(h1h), a1 = *(const f16x8*)(h1h + 8);
      f16x8 q0 = *(const f16x8*)(h1l), q1 = *(const f16x8*)(h1l + 8);
      float s = 0.f;
#pragma unroll
      for (int e2 = 0; e2 < 8; ++e2) {
        s = fmaf((float)a0[e2] + (float)q0[e2], wr[e2], s);
        s = fmaf((float)a1[e2] + (float)q1[e2], wr[8 + e2], s);
      }
#pragma unroll
      for (int off = 1; off < 16; off <<= 1) s += __shfl_xor(s, off);
      if ((tid & 15) == 0)
        p.out[((size_t)(bid * 16 + hm) * DT_ + t) * 2 + hpp] = s + bo;
    }
    pb ^= 1;
  }
}

// ---------------- host launcher ----------------
extern "C" void kernel_launch(void* const* d_in, const int* in_sizes, int n_in,
                              void* d_out, int out_size, void* d_ws,
                              size_t ws_size, hipStream_t stream) {
  (void)in_sizes; (void)n_in; (void)out_size; (void)ws_size;
  auto F = [&](int i) { return (const float*)d_in[i]; };
  Par p{};
  p.x = F(0);
  // 9 recurrent matrices in fragment-buffer order + dec_Wih0
  p.big_src[0] = F(10);  // nbr_Whh0
  p.big_src[1] = F(13);  // nbr_Wih1
  p.big_src[2] = F(14);  // nbr_Whh1
  p.big_src[3] = F(2);   // ego_Whh0
  p.big_src[4] = F(5);   // ego_Wih1
  p.big_src[5] = F(6);   // ego_Whh1
  p.big_src[6] = F(18);  // dec_Whh0
  p.big_src[7] = F(21);  // dec_Wih1
  p.big_src[8] = F(22);  // dec_Whh1
  p.big_src[9] = F(17);  // dec_Wih0
  p.ih0_src[0] = F(9);   // nbr_Wih0
  p.ih0_src[1] = F(1);   // ego_Wih0
  p.att_src[0] = F(25); p.att_src[1] = F(26);
  p.att_src[2] = F(27); p.att_src[3] = F(28);
  p.Wconv = F(33);
  p.bih[0] = F(11); p.bhh[0] = F(12);  // nbr l0
  p.bih[1] = F(15); p.bhh[1] = F(16);  // nbr l1
  p.bih[2] = F(3);  p.bhh[2] = F(4);   // ego l0
  p.bih[3] = F(7);  p.bhh[3] = F(8);   // ego l1
  p.bih[4] = F(19); p.bhh[4] = F(20);  // dec l0
  p.bih[5] = F(23); p.bhh[5] = F(24);  // dec l1
  p.bq = F(29); p.bk = F(30); p.bv = F(31); p.bao = F(32);
  p.bconv = F(34); p.Wout = F(35); p.bout = F(36);
  p.ws = (float*)d_ws;
  p.out = (float*)d_out;

  hipLaunchKernelGGL(prep_kernel, dim3(1024), dim3(256), 0, stream, p);
  hipLaunchKernelGGL(encoder_kernel, dim3(NBLK_ENC), dim3(512), 0, stream, p);
  hipLaunchKernelGGL(attn_kernel, dim3(512), dim3(256), 0, stream, p);
  hipLaunchKernelGGL(conv_kernel, dim3(B_), dim3(256), 0, stream, p);
  hipLaunchKernelGGL(decoder_kernel, dim3(NBLK_DEC), dim3(512), 0, stream, p);
}

// Round 4
// 7209.283 us; speedup vs baseline: 1.3849x; 1.1384x over previous
//
#include <hip/hip_runtime.h>

#define DEV __device__ __forceinline__

typedef _Float16 f16x8 __attribute__((ext_vector_type(8)));
typedef float f32x4 __attribute__((ext_vector_type(4)));

// ---- problem dims ----
constexpr int B_ = 256, A_ = 20, T_ = 50, IN_ = 6;
constexpr int H_ = 256, G_ = 1024, NH_ = 8, DT_ = 60;
constexpr int NN_ = 19;
constexpr int NB_ = B_ * NN_;   // 4864
constexpr int XROW = T_ * IN_;  // 300

// encoder: M=32/block. 160 blocks = 152 nbr + 8 ego.
// ego blocks live at bid % 8 == 0 (bid<64) -> all ego on XCD0; XCD1-7 pure nbr.
constexpr int NBLK_ENC = 160;
// decoder: M=16/block, 16 blocks
constexpr int NBLK_DEC = 16;

// ---- ws byte offsets ----
// B-fragment layout for W^T (j=gate*256+col): frag[((jt*8+kt)*64+l)*8+e]
//   = (fp16) W[n*256+k], n=jt*16+(l&15), k=kt*32+(l>>4)*8+e
constexpr size_t FB = 64ull * 8 * 64 * 8 * 2;  // 512KB per 1024x256 matrix
constexpr size_t FS = 64ull * 64 * 8 * 2;      // 64KB per 1024x6 (K pad 32)
constexpr size_t O_F_NHH0 = 0;
constexpr size_t O_F_NIH1 = O_F_NHH0 + FB;
constexpr size_t O_F_NHH1 = O_F_NIH1 + FB;
constexpr size_t O_F_EHH0 = O_F_NHH1 + FB;
constexpr size_t O_F_EIH1 = O_F_EHH0 + FB;
constexpr size_t O_F_EHH1 = O_F_EIH1 + FB;
constexpr size_t O_F_DHH0 = O_F_EHH1 + FB;
constexpr size_t O_F_DIH1 = O_F_DHH0 + FB;
constexpr size_t O_F_DHH1 = O_F_DIH1 + FB;
constexpr size_t O_F_NIH0 = O_F_DHH1 + FB;
constexpr size_t O_F_EIH0 = O_F_NIH0 + FS;
constexpr size_t B_BC    = O_F_EIH0 + FS;            // 6*1024 fp32
constexpr size_t B_ATT   = B_BC + 6 * 1024 * 4;      // 4 x [k][256] fp32
constexpr size_t B_WCT   = B_ATT + 4 * 65536 * 4;    // [2][512][256] fp32
constexpr size_t B_DIH0T = B_WCT + 2 * 512 * 256 * 4;// [k][1024] fp32
constexpr size_t B_NBRH1 = B_DIH0T + 256 * 1024 * 4; // [2][4864][256] fp32
constexpr size_t B_COMB  = B_NBRH1 + 2ull * NB_ * H_ * 4;  // [2][256][512]
constexpr size_t B_PRE0  = B_COMB + 2ull * B_ * 512 * 4;   // [256][1024]

struct Par {
  const float* x;
  const float* big_src[10];
  const float* ih0_src[2];
  const float* att_src[4];
  const float* Wconv;
  const float* bih[6];
  const float* bhh[6];
  const float *bq, *bk, *bv, *bao, *bconv, *Wout, *bout;
  float* ws;
  float* out;
};

// ---------------- prep: fragment packing + transposes + bias sums ----------------
__global__ void prep_kernel(Par p) {
  char* wsb = (char*)p.ws;
  const size_t NBIG = 9ull * 262144;
  const size_t NIH0 = 2ull * 32768;
  const size_t NBC  = 6144;
  const size_t NATT = 4ull * 65536;
  const size_t NWCT = 2ull * 512 * 256;
  const size_t NDIH = 256ull * 1024;
  const size_t total = NBIG + NIH0 + NBC + NATT + NWCT + NDIH;
  for (size_t i = (size_t)blockIdx.x * blockDim.x + threadIdx.x; i < total;
       i += (size_t)gridDim.x * blockDim.x) {
    size_t idx = i;
    if (idx < NBIG) {
      int mi = (int)(idx / 262144);
      size_t f = idx - (size_t)mi * 262144;
      int e = (int)(f & 7), l = (int)((f >> 3) & 63);
      int kt = (int)((f >> 9) & 7), jt = (int)(f >> 12);
      int n = jt * 16 + (l & 15), k = kt * 32 + (l >> 4) * 8 + e;
      ((_Float16*)(wsb + O_F_NHH0))[idx] =
          (_Float16)p.big_src[mi][(size_t)n * 256 + k];
      continue;
    }
    idx -= NBIG;
    if (idx < NIH0) {
      int mi = (int)(idx >> 15);
      size_t f = idx & 32767;
      int e = (int)(f & 7), l = (int)((f >> 3) & 63), jt = (int)(f >> 9);
      int n = jt * 16 + (l & 15), k = (l >> 4) * 8 + e;
      ((_Float16*)(wsb + O_F_NIH0))[idx] =
          (_Float16)(k < 6 ? p.ih0_src[mi][(size_t)n * 6 + k] : 0.f);
      continue;
    }
    idx -= NIH0;
    if (idx < NBC) {
      int li = (int)(idx >> 10), jj = (int)(idx & 1023);
      ((float*)(wsb + B_BC))[idx] = p.bih[li][jj] + p.bhh[li][jj];
      continue;
    }
    idx -= NBC;
    if (idx < NATT) {
      int mi = (int)(idx >> 16);
      size_t f = idx & 65535;
      int k = (int)(f >> 8), c = (int)(f & 255);
      ((float*)(wsb + B_ATT))[idx] = p.att_src[mi][(size_t)c * 256 + k];
      continue;
    }
    idx -= NATT;
    if (idx < NWCT) {
      int dt = (int)(idx / (512 * 256));
      size_t f = idx - (size_t)dt * 512 * 256;
      int c = (int)(f >> 8), o = (int)(f & 255);
      ((float*)(wsb + B_WCT))[idx] = p.Wconv[(size_t)o * 1536 + (size_t)c * 3 + dt];
      continue;
    }
    idx -= NWCT;
    {
      int k = (int)(idx >> 10), j = (int)(idx & 1023);
      ((float*)(wsb + B_DIH0T))[idx] = p.big_src[9][(size_t)j * 256 + k];
    }
  }
}

// ---------------- building blocks ----------------
DEV float fsig(float x) { return 1.f / (1.f + __expf(-x)); }
DEV float ftanh(float x) { return 1.f - 2.f / (__expf(2.f * x) + 1.f); }

DEV void loadB8(f16x8 (&dst)[8], const _Float16* __restrict__ WB, int kt,
                int w, int l) {
#pragma unroll
  for (int q = 0; q < 8; ++q) {
    int jt = (q >> 1) * 16 + w * 2 + (q & 1);
    dst[q] = *(const f16x8*)(WB + ((size_t)(jt * 8 + kt) * 64 + l) * 8);
  }
}
DEV void loadB8_ih0(f16x8 (&dst)[8], const _Float16* __restrict__ WB, int w,
                    int l) {
#pragma unroll
  for (int q = 0; q < 8; ++q) {
    int jt = (q >> 1) * 16 + w * 2 + (q & 1);
    dst[q] = *(const f16x8*)(WB + ((size_t)jt * 64 + l) * 8);
  }
}

template <int MT>
DEV void mm_chunk(f32x4 (&acc)[MT][4][2], const _Float16* Hhi,
                  const _Float16* Hlo, int kt, const f16x8 (&bb)[8], int m15,
                  int khi) {
  f16x8 ah[MT], al[MT];
#pragma unroll
  for (int mt = 0; mt < MT; ++mt) {
    int off = (mt * 16 + m15) * 264 + kt * 32 + khi;
    ah[mt] = *(const f16x8*)(Hhi + off);
    al[mt] = *(const f16x8*)(Hlo + off);
  }
#pragma unroll
  for (int q = 0; q < 8; ++q) {
    int g = q >> 1, t2 = q & 1;
#pragma unroll
    for (int mt = 0; mt < MT; ++mt) {
      acc[mt][g][t2] = __builtin_amdgcn_mfma_f32_16x16x32_f16(
          ah[mt], bb[q], acc[mt][g][t2], 0, 0, 0);
      acc[mt][g][t2] = __builtin_amdgcn_mfma_f32_16x16x32_f16(
          al[mt], bb[q], acc[mt][g][t2], 0, 0, 0);
    }
  }
}

template <int MT>
DEV void acc_init(f32x4 (&acc)[MT][4][2], const float (&b)[4][2]) {
#pragma unroll
  for (int mt = 0; mt < MT; ++mt)
#pragma unroll
    for (int g = 0; g < 4; ++g)
#pragma unroll
      for (int t2 = 0; t2 < 2; ++t2) {
        f32x4 v = {b[g][t2], b[g][t2], b[g][t2], b[g][t2]};
        acc[mt][g][t2] = v;
      }
}

template <int MT>
DEV void cell_compute(f32x4 (&acc)[MT][4][2], f32x4 (&c)[MT][2],
                      float (&hv)[MT][2][4]) {
#pragma unroll
  for (int mt = 0; mt < MT; ++mt)
#pragma unroll
    for (int t2 = 0; t2 < 2; ++t2)
#pragma unroll
      for (int r = 0; r < 4; ++r) {
        float iv = fsig(acc[mt][0][t2][r]);
        float fv = fsig(acc[mt][1][t2][r]);
        float gv = ftanh(acc[mt][2][t2][r]);
        float ov = fsig(acc[mt][3][t2][r]);
        float cv = fv * c[mt][t2][r] + iv * gv;
        c[mt][t2][r] = cv;
        hv[mt][t2][r] = ov * ftanh(cv);
      }
}

template <int MT>
DEV void writeH(const float (&hv)[MT][2][4], _Float16* Hhi, _Float16* Hlo,
                int w, int l) {
  const int rbase = (l >> 4) * 4, m15 = l & 15;
#pragma unroll
  for (int mt = 0; mt < MT; ++mt)
#pragma unroll
    for (int t2 = 0; t2 < 2; ++t2)
#pragma unroll
      for (int r = 0; r < 4; ++r) {
        int m = mt * 16 + rbase + r, col = w * 32 + t2 * 16 + m15;
        float hvv = hv[mt][t2][r];
        _Float16 hi = (_Float16)hvv;
        Hhi[m * 264 + col] = hi;
        Hlo[m * 264 + col] = (_Float16)(hvv - (float)hi);
      }
}

// chunk macro: consume bc, prefetch (WBn,ktn) into bn
#define CHUNK(bc, bn, WBn, ktn, Hhi, Hlo, kt)   \
  loadB8(bn, WBn, ktn, w, l);                   \
  mm_chunk<MTC>(acc, Hhi, Hlo, kt, bc, m15, khi);
// 8-chunk group over kt=0..7 reading (Hhi,Hlo); prefetch chain ends at (WBn,0)
#define G8(WBc, WBn, Hhi, Hlo)                  \
  CHUNK(bpA, bpB, WBc, 1, Hhi, Hlo, 0)          \
  CHUNK(bpB, bpA, WBc, 2, Hhi, Hlo, 1)          \
  CHUNK(bpA, bpB, WBc, 3, Hhi, Hlo, 2)          \
  CHUNK(bpB, bpA, WBc, 4, Hhi, Hlo, 3)          \
  CHUNK(bpA, bpB, WBc, 5, Hhi, Hlo, 4)          \
  CHUNK(bpB, bpA, WBc, 6, Hhi, Hlo, 5)          \
  CHUNK(bpA, bpB, WBc, 7, Hhi, Hlo, 6)          \
  CHUNK(bpB, bpA, WBn, 0, Hhi, Hlo, 7)

// ---------------- encoder: fused ego+nbr 2-layer LSTM (MFMA, pipelined) ----------------
__global__ __launch_bounds__(512, 2) void encoder_kernel(Par p) {
  constexpr int MTC = 2;
  __shared__ _Float16 Hs[2][2][32][264];  // [layer][hi/lo][m][k pad]
  __shared__ _Float16 XF[2][512];         // [mt][lane*8] A-frag of x (K pad 32)
  const int tid = threadIdx.x, w = tid >> 6, l = tid & 63;
  const int m15 = l & 15, khi = (l >> 4) * 8;
  const int bid = blockIdx.x;
  const bool ego = ((bid & 7) == 0) && (bid < 64);
  int nid = 0, eidx = 0;
  if (ego) {
    eidx = bid >> 3;
  } else {
    int nb = (bid + 7) >> 3;
    if (nb > 8) nb = 8;
    nid = bid - nb;
  }
  char* wsb = (char*)p.ws;
  const _Float16* WB_hh0 = (const _Float16*)(wsb + (ego ? O_F_EHH0 : O_F_NHH0));
  const _Float16* WB_ih1 = (const _Float16*)(wsb + (ego ? O_F_EIH1 : O_F_NIH1));
  const _Float16* WB_hh1 = (const _Float16*)(wsb + (ego ? O_F_EHH1 : O_F_NHH1));
  const _Float16* WB_ih0 = (const _Float16*)(wsb + (ego ? O_F_EIH0 : O_F_NIH0));

  for (int i = tid; i < 2 * 2 * 32 * 264; i += 512)
    ((_Float16*)Hs)[i] = (_Float16)0.f;
  for (int i = tid; i < 1024; i += 512) ((_Float16*)XF)[i] = (_Float16)0.f;

  const float* bcb = (const float*)(wsb + B_BC) + (ego ? 2048 : 0);
  float b0v[4][2], b1v[4][2];
#pragma unroll
  for (int g = 0; g < 4; ++g)
#pragma unroll
    for (int t2 = 0; t2 < 2; ++t2) {
      int j = g * 256 + w * 32 + t2 * 16 + m15;
      b0v[g][t2] = bcb[j];
      b1v[g][t2] = bcb[1024 + j];
    }

  // x staging: tid<192 -> (m32 0..31, kx 0..5)
  const int m32 = tid / 6, kx = tid - m32 * 6;
  const float* xp = nullptr;
  int xslot = 0;
  if (tid < 192) {
    int row;
    if (!ego) {
      int n = nid * 32 + m32;
      int q = n / 19;
      row = q * 20 + 1 + (n - q * 19);
    } else {
      row = (eidx * 32 + m32) * 20;
    }
    xp = p.x + (size_t)row * XROW + kx;
    xslot = (m32 >> 4) * 512 + (m32 & 15) * 8 + kx;
  }

  __syncthreads();
  if (tid < 192) ((_Float16*)XF)[xslot] = (_Float16)xp[0];

  f16x8 bI[8], bpA[8], bpB[8];
  loadB8_ih0(bI, WB_ih0, w, l);   // t-invariant, lives in regs all 50 steps
  loadB8(bpA, WB_hh0, 0, w, l);   // prologue of the prefetch chain
  __syncthreads();

  f32x4 c0[2][2] = {}, c1[2][2] = {};
  float h0v[2][2][4], h1v[2][2][4];

  for (int t = 0; t < T_; ++t) {
    // ---- layer 0 ----
    f32x4 acc[MTC][4][2];
    acc_init<MTC>(acc, b0v);
    {  // ih0 chunk (x is exact in fp16 path per round-3 validation)
      f16x8 a0 = *(const f16x8*)(&XF[0][l * 8]);
      f16x8 a1 = *(const f16x8*)(&XF[1][l * 8]);
#pragma unroll
      for (int q = 0; q < 8; ++q) {
        acc[0][q >> 1][q & 1] = __builtin_amdgcn_mfma_f32_16x16x32_f16(
            a0, bI[q], acc[0][q >> 1][q & 1], 0, 0, 0);
        acc[1][q >> 1][q & 1] = __builtin_amdgcn_mfma_f32_16x16x32_f16(
            a1, bI[q], acc[1][q >> 1][q & 1], 0, 0, 0);
      }
    }
    G8(WB_hh0, WB_ih1, &Hs[0][0][0][0], &Hs[0][1][0][0])
    cell_compute<MTC>(acc, c0, h0v);
    __syncthreads();  // B1: all reads of Hs[0] done
    writeH<MTC>(h0v, &Hs[0][0][0][0], &Hs[0][1][0][0], w, l);
    if (t < T_ - 1 && tid < 192)
      ((_Float16*)XF)[xslot] = (_Float16)xp[(t + 1) * IN_];
    __syncthreads();  // B2: h0_new + x_{t+1} visible

    // ---- layer 1 ----
    acc_init<MTC>(acc, b1v);
    G8(WB_ih1, WB_hh1, &Hs[0][0][0][0], &Hs[0][1][0][0])   // h0 NEW
    G8(WB_hh1, WB_hh0, &Hs[1][0][0][0], &Hs[1][1][0][0])   // h1 OLD; wraps to next step's hh0
    cell_compute<MTC>(acc, c1, h1v);
    __syncthreads();  // B3: reads of Hs[1] done
    writeH<MTC>(h1v, &Hs[1][0][0][0], &Hs[1][1][0][0], w, l);
    if (t >= T_ - 2) {  // only t=48,49 consumed downstream
      int tg = t - (T_ - 2);
      const int rbase = (l >> 4) * 4;
#pragma unroll
      for (int mt = 0; mt < 2; ++mt)
#pragma unroll
        for (int t2 = 0; t2 < 2; ++t2)
#pragma unroll
          for (int r = 0; r < 4; ++r) {
            int mloc = mt * 16 + rbase + r, col = w * 32 + t2 * 16 + m15;
            if (!ego) {
              int n = nid * 32 + mloc;
              ((float*)(wsb + B_NBRH1))[((size_t)tg * NB_ + n) * H_ + col] =
                  h1v[mt][t2][r];
            } else {
              int b = eidx * 32 + mloc;
              ((float*)(wsb + B_COMB))[((size_t)tg * B_ + b) * 512 + col] =
                  h1v[mt][t2][r];
            }
          }
    }
    __syncthreads();  // B4
  }
}

// ---------------- attention at t=48,49 (one block per (t2,b)) ----------------
__global__ __launch_bounds__(256) void attn_kernel(Par p) {
  __shared__ float kk[NN_][H_];
  __shared__ float vv[NN_][H_];
  __shared__ float e[H_];
  __shared__ float q[H_];
  __shared__ float att[H_];
  __shared__ float sc[NH_][NN_];
  const int tid = threadIdx.x;
  const int bid = blockIdx.x;
  const int t2 = bid >> 8, b = bid & 255;
  char* wsb = (char*)p.ws;
  const float* attw = (const float*)(wsb + B_ATT);
  float* comb = (float*)(wsb + B_COMB);

  e[tid] = comb[((size_t)t2 * B_ + b) * 512 + tid];
  __syncthreads();
  {
    float a = p.bq[tid];
    const float* Wq = attw + tid;
    for (int k0 = 0; k0 < H_; k0 += 4) {
      const float4 e4 = *reinterpret_cast<const float4*>(&e[k0]);
      a = fmaf(Wq[(size_t)k0 * 256], e4.x, a);
      a = fmaf(Wq[(size_t)(k0 + 1) * 256], e4.y, a);
      a = fmaf(Wq[(size_t)(k0 + 2) * 256], e4.z, a);
      a = fmaf(Wq[(size_t)(k0 + 3) * 256], e4.w, a);
    }
    q[tid] = a;
  }
  {
    float ak[NN_], av[NN_];
#pragma unroll
    for (int n = 0; n < NN_; ++n) { ak[n] = p.bk[tid]; av[n] = p.bv[tid]; }
    const float* Wk = attw + 65536 + tid;
    const float* Wv = attw + 2 * 65536 + tid;
    const float* hb = (const float*)(wsb + B_NBRH1) +
                      ((size_t)t2 * NB_ + (size_t)b * NN_) * H_;
    for (int k0 = 0; k0 < H_; k0 += 4) {
      float wk0 = Wk[(size_t)k0 * 256], wk1 = Wk[(size_t)(k0 + 1) * 256];
      float wk2 = Wk[(size_t)(k0 + 2) * 256], wk3 = Wk[(size_t)(k0 + 3) * 256];
      float wv0 = Wv[(size_t)k0 * 256], wv1 = Wv[(size_t)(k0 + 1) * 256];
      float wv2 = Wv[(size_t)(k0 + 2) * 256], wv3 = Wv[(size_t)(k0 + 3) * 256];
#pragma unroll
      for (int n = 0; n < NN_; ++n) {
        const float4 h4 =
            *reinterpret_cast<const float4*>(hb + (size_t)n * H_ + k0);
        ak[n] = fmaf(wk0, h4.x, ak[n]);
        ak[n] = fmaf(wk1, h4.y, ak[n]);
        ak[n] = fmaf(wk2, h4.z, ak[n]);
        ak[n] = fmaf(wk3, h4.w, ak[n]);
        av[n] = fmaf(wv0, h4.x, av[n]);
        av[n] = fmaf(wv1, h4.y, av[n]);
        av[n] = fmaf(wv2, h4.z, av[n]);
        av[n] = fmaf(wv3, h4.w, av[n]);
      }
    }
#pragma unroll
    for (int n = 0; n < NN_; ++n) { kk[n][tid] = ak[n]; vv[n][tid] = av[n]; }
  }
  __syncthreads();
  if (tid < NH_ * NN_) {
    int h = tid / NN_, n = tid - h * NN_;
    float s = 0.f;
#pragma unroll
    for (int d = 0; d < 32; ++d) s = fmaf(q[h * 32 + d], kk[n][h * 32 + d], s);
    sc[h][n] = s * 0.17677669529663687f;
  }
  __syncthreads();
  if (tid < NH_) {
    float mx = sc[tid][0];
#pragma unroll
    for (int n = 1; n < NN_; ++n) mx = fmaxf(mx, sc[tid][n]);
    float den = 0.f, wn[NN_];
#pragma unroll
    for (int n = 0; n < NN_; ++n) {
      wn[n] = __expf(sc[tid][n] - mx);
      den += wn[n];
    }
    float r = 1.f / den;
#pragma unroll
    for (int n = 0; n < NN_; ++n) sc[tid][n] = wn[n] * r;
  }
  __syncthreads();
  {
    int h = tid >> 5;
    float a = 0.f;
#pragma unroll
    for (int n = 0; n < NN_; ++n) a = fmaf(sc[h][n], vv[n][tid], a);
    att[tid] = a;
  }
  __syncthreads();
  {
    float a = p.bao[tid];
    const float* Wao = attw + 3 * 65536 + tid;
    for (int k0 = 0; k0 < H_; k0 += 4) {
      const float4 a4 = *reinterpret_cast<const float4*>(&att[k0]);
      a = fmaf(Wao[(size_t)k0 * 256], a4.x, a);
      a = fmaf(Wao[(size_t)(k0 + 1) * 256], a4.y, a);
      a = fmaf(Wao[(size_t)(k0 + 2) * 256], a4.z, a);
      a = fmaf(Wao[(size_t)(k0 + 3) * 256], a4.w, a);
    }
    comb[((size_t)t2 * B_ + b) * 512 + 256 + tid] = a;
  }
}

// -------- conv (only t=49 output live) + decoder layer-0 x-part --------
__global__ __launch_bounds__(256) void conv_kernel(Par p) {
  __shared__ float cl[2][512];
  __shared__ float tf[H_];
  const int b = blockIdx.x, tid = threadIdx.x;
  char* wsb = (char*)p.ws;
  const float* comb = (const float*)(wsb + B_COMB);
  for (int idx = tid; idx < 1024; idx += 256) {
    int t2 = idx >> 9, c = idx & 511;
    cl[t2][c] = comb[((size_t)t2 * B_ + b) * 512 + c];
  }
  __syncthreads();
  {
    float a = p.bconv[tid];
    const float* W0 = (const float*)(wsb + B_WCT) + tid;
    const float* W1 = W0 + 512 * 256;
    for (int c = 0; c < 512; ++c) {
      a = fmaf(cl[0][c], W0[(size_t)c * 256], a);
      a = fmaf(cl[1][c], W1[(size_t)c * 256], a);
    }
    tf[tid] = a;
  }
  __syncthreads();
  {
    float accp[4];
    const float* bcd0 = (const float*)(wsb + B_BC) + 4096;
#pragma unroll
    for (int g = 0; g < 4; ++g) accp[g] = bcd0[g * 256 + tid];
    const float* Wt = (const float*)(wsb + B_DIH0T) + tid;
    for (int k0 = 0; k0 < H_; k0 += 4) {
      const float4 t4 = *reinterpret_cast<const float4*>(&tf[k0]);
      float tv[4] = {t4.x, t4.y, t4.z, t4.w};
#pragma unroll
      for (int kq = 0; kq < 4; ++kq) {
        const float* wp = Wt + (size_t)(k0 + kq) * G_;
        accp[0] = fmaf(wp[0], tv[kq], accp[0]);
        accp[1] = fmaf(wp[256], tv[kq], accp[1]);
        accp[2] = fmaf(wp[512], tv[kq], accp[2]);
        accp[3] = fmaf(wp[768], tv[kq], accp[3]);
      }
    }
    float* pre0 = (float*)(wsb + B_PRE0);
#pragma unroll
    for (int g = 0; g < 4; ++g) pre0[(size_t)b * G_ + g * 256 + tid] = accp[g];
  }
}

// ---------------- decoder: 2-layer LSTM, 60 steps (MFMA, pipelined) + head ----------------
__global__ __launch_bounds__(512, 2) void decoder_kernel(Par p) {
  constexpr int MTC = 1;
  __shared__ _Float16 Hs[2][2][16][264];
  const int tid = threadIdx.x, w = tid >> 6, l = tid & 63;
  const int m15 = l & 15, khi = (l >> 4) * 8;
  const int bid = blockIdx.x;
  char* wsb = (char*)p.ws;
  const _Float16* WB_hh0 = (const _Float16*)(wsb + O_F_DHH0);
  const _Float16* WB_ih1 = (const _Float16*)(wsb + O_F_DIH1);
  const _Float16* WB_hh1 = (const _Float16*)(wsb + O_F_DHH1);

  for (int i = tid; i < 2 * 2 * 16 * 264; i += 512)
    ((_Float16*)Hs)[i] = (_Float16)0.f;

  const float* bcd1 = (const float*)(wsb + B_BC) + 5120;
  float b1v[4][2];
  f32x4 pre[4][2];
  {
    const float* pre0 = (const float*)(wsb + B_PRE0);
    const int rbase = (l >> 4) * 4;
#pragma unroll
    for (int g = 0; g < 4; ++g)
#pragma unroll
      for (int t2 = 0; t2 < 2; ++t2) {
        int j = g * 256 + w * 32 + t2 * 16 + m15;
        b1v[g][t2] = bcd1[j];
#pragma unroll
        for (int r = 0; r < 4; ++r)
          pre[g][t2][r] = pre0[(size_t)(bid * 16 + rbase + r) * G_ + j];
      }
  }
  const int hm = tid >> 5, hpp = (tid >> 4) & 1, hkc = tid & 15;
  float wr[16], bo;
  {
#pragma unroll
    for (int e2 = 0; e2 < 16; ++e2) wr[e2] = p.Wout[hpp * 256 + hkc * 16 + e2];
    bo = p.bout[hpp];
  }

  f16x8 bpA[8], bpB[8];
  loadB8(bpA, WB_hh0, 0, w, l);
  f32x4 c0[1][2] = {}, c1[1][2] = {};
  float h0v[1][2][4], h1v[1][2][4];
  __syncthreads();

  for (int t = 0; t < DT_; ++t) {
    f32x4 acc[MTC][4][2];
#pragma unroll
    for (int g = 0; g < 4; ++g)
#pragma unroll
      for (int t2 = 0; t2 < 2; ++t2) acc[0][g][t2] = pre[g][t2];
    G8(WB_hh0, WB_ih1, &Hs[0][0][0][0], &Hs[0][1][0][0])
    cell_compute<MTC>(acc, c0, h0v);
    __syncthreads();  // B1
    writeH<MTC>(h0v, &Hs[0][0][0][0], &Hs[0][1][0][0], w, l);
    __syncthreads();  // B2
    acc_init<MTC>(acc, b1v);
    G8(WB_ih1, WB_hh1, &Hs[0][0][0][0], &Hs[0][1][0][0])
    G8(WB_hh1, WB_hh0, &Hs[1][0][0][0], &Hs[1][1][0][0])
    cell_compute<MTC>(acc, c1, h1v);
    __syncthreads();  // B3
    writeH<MTC>(h1v, &Hs[1][0][0][0], &Hs[1][1][0][0], w, l);
    __syncthreads();  // B4
    {  // head: pred[m][pp] = (h1hi+h1lo) . Wout[pp] + bout[pp]
      const _Float16* h1h = &Hs[1][0][hm][hkc * 16];
      const _Float16* h1l = &Hs[1][1][hm][hkc * 16];
      f16x8 a0 = *(const f16x8*)(h1h), a1 = *(const f16x8*)(h1h + 8);
      f16x8 q0 = *(const f16x8*)(h1l), q1 = *(const f16x8*)(h1l + 8);
      float s = 0.f;
#pragma unroll
      for (int e2 = 0; e2 < 8; ++e2) {
        s = fmaf((float)a0[e2] + (float)q0[e2], wr[e2], s);
        s = fmaf((float)a1[e2] + (float)q1[e2], wr[8 + e2], s);
      }
#pragma unroll
      for (int off = 1; off < 16; off <<= 1) s += __shfl_xor(s, off);
      if ((tid & 15) == 0)
        p.out[((size_t)(bid * 16 + hm) * DT_ + t) * 2 + hpp] = s + bo;
    }
  }
}

// ---------------- host launcher ----------------
extern "C" void kernel_launch(void* const* d_in, const int* in_sizes, int n_in,
                              void* d_out, int out_size, void* d_ws,
                              size_t ws_size, hipStream_t stream) {
  (void)in_sizes; (void)n_in; (void)out_size; (void)ws_size;
  auto F = [&](int i) { return (const float*)d_in[i]; };
  Par p{};
  p.x = F(0);
  p.big_src[0] = F(10);  // nbr_Whh0
  p.big_src[1] = F(13);  // nbr_Wih1
  p.big_src[2] = F(14);  // nbr_Whh1
  p.big_src[3] = F(2);   // ego_Whh0
  p.big_src[4] = F(5);   // ego_Wih1
  p.big_src[5] = F(6);   // ego_Whh1
  p.big_src[6] = F(18);  // dec_Whh0
  p.big_src[7] = F(21);  // dec_Wih1
  p.big_src[8] = F(22);  // dec_Whh1
  p.big_src[9] = F(17);  // dec_Wih0
  p.ih0_src[0] = F(9);   // nbr_Wih0
  p.ih0_src[1] = F(1);   // ego_Wih0
  p.att_src[0] = F(25); p.att_src[1] = F(26);
  p.att_src[2] = F(27); p.att_src[3] = F(28);
  p.Wconv = F(33);
  p.bih[0] = F(11); p.bhh[0] = F(12);
  p.bih[1] = F(15); p.bhh[1] = F(16);
  p.bih[2] = F(3);  p.bhh[2] = F(4);
  p.bih[3] = F(7);  p.bhh[3] = F(8);
  p.bih[4] = F(19); p.bhh[4] = F(20);
  p.bih[5] = F(23); p.bhh[5] = F(24);
  p.bq = F(29); p.bk = F(30); p.bv = F(31); p.bao = F(32);
  p.bconv = F(34); p.Wout = F(35); p.bout = F(36);
  p.ws = (float*)d_ws;
  p.out = (float*)d_out;

  hipLaunchKernelGGL(prep_kernel, dim3(1024), dim3(256), 0, stream, p);
  hipLaunchKernelGGL(encoder_kernel, dim3(NBLK_ENC), dim3(512), 0, stream, p);
  hipLaunchKernelGGL(attn_kernel, dim3(512), dim3(256), 0, stream, p);
  hipLaunchKernelGGL(conv_kernel, dim3(B_), dim3(256), 0, stream, p);
  hipLaunchKernelGGL(decoder_kernel, dim3(NBLK_DEC), dim3(512), 0, stream, p);
}

// Round 6
// 7204.568 us; speedup vs baseline: 1.3858x; 1.0007x over previous
//
#include <hip/hip_runtime.h>

#define DEV __device__ __forceinline__

typedef _Float16 f16x8 __attribute__((ext_vector_type(8)));
typedef float f32x4 __attribute__((ext_vector_type(4)));

// ---- problem dims ----
constexpr int B_ = 256, A_ = 20, T_ = 50, IN_ = 6;
constexpr int H_ = 256, G_ = 1024, NH_ = 8, DT_ = 60;
constexpr int NN_ = 19;
constexpr int NB_ = B_ * NN_;   // 4864
constexpr int XROW = T_ * IN_;  // 300

// encoder: M=32/block. 160 blocks = 152 nbr + 8 ego.
// ego blocks live at bid % 8 == 0 (bid<64) -> all ego on XCD0; XCD1-7 pure nbr.
constexpr int NBLK_ENC = 160;
// decoder: M=16/block, 16 blocks
constexpr int NBLK_DEC = 16;

// ---- ws byte offsets ----
// B-fragment layout for W^T (j=gate*256+col): frag[((jt*8+kt)*64+l)*8+e]
//   = (fp16) W[n*256+k], n=jt*16+(l&15), k=kt*32+(l>>4)*8+e
constexpr size_t FB = 64ull * 8 * 64 * 8 * 2;  // 512KB per 1024x256 matrix
constexpr size_t FS = 64ull * 64 * 8 * 2;      // 64KB per 1024x6 (K pad 32)
constexpr size_t O_F_NHH0 = 0;
constexpr size_t O_F_NIH1 = O_F_NHH0 + FB;
constexpr size_t O_F_NHH1 = O_F_NIH1 + FB;
constexpr size_t O_F_EHH0 = O_F_NHH1 + FB;
constexpr size_t O_F_EIH1 = O_F_EHH0 + FB;
constexpr size_t O_F_EHH1 = O_F_EIH1 + FB;
constexpr size_t O_F_DHH0 = O_F_EHH1 + FB;
constexpr size_t O_F_DIH1 = O_F_DHH0 + FB;
constexpr size_t O_F_DHH1 = O_F_DIH1 + FB;
constexpr size_t O_F_NIH0 = O_F_DHH1 + FB;
constexpr size_t O_F_EIH0 = O_F_NIH0 + FS;
constexpr size_t B_BC    = O_F_EIH0 + FS;            // 6*1024 fp32
constexpr size_t B_ATT   = B_BC + 6 * 1024 * 4;      // 4 x [k][256] fp32
constexpr size_t B_WCT   = B_ATT + 4 * 65536 * 4;    // [2][512][256] fp32
constexpr size_t B_DIH0T = B_WCT + 2 * 512 * 256 * 4;// [k][1024] fp32
constexpr size_t B_NBRH1 = B_DIH0T + 256 * 1024 * 4; // [2][4864][256] fp32
constexpr size_t B_COMB  = B_NBRH1 + 2ull * NB_ * H_ * 4;  // [2][256][512]
constexpr size_t B_PRE0  = B_COMB + 2ull * B_ * 512 * 4;   // [256][1024]

struct Par {
  const float* x;
  const float* big_src[10];
  const float* ih0_src[2];
  const float* att_src[4];
  const float* Wconv;
  const float* bih[6];
  const float* bhh[6];
  const float *bq, *bk, *bv, *bao, *bconv, *Wout, *bout;
  float* ws;
  float* out;
};

// ---------------- prep: fragment packing + transposes + bias sums ----------------
__global__ void prep_kernel(Par p) {
  char* wsb = (char*)p.ws;
  const size_t NBIG = 9ull * 262144;
  const size_t NIH0 = 2ull * 32768;
  const size_t NBC  = 6144;
  const size_t NATT = 4ull * 65536;
  const size_t NWCT = 2ull * 512 * 256;
  const size_t NDIH = 256ull * 1024;
  const size_t total = NBIG + NIH0 + NBC + NATT + NWCT + NDIH;
  for (size_t i = (size_t)blockIdx.x * blockDim.x + threadIdx.x; i < total;
       i += (size_t)gridDim.x * blockDim.x) {
    size_t idx = i;
    if (idx < NBIG) {
      int mi = (int)(idx / 262144);
      size_t f = idx - (size_t)mi * 262144;
      int e = (int)(f & 7), l = (int)((f >> 3) & 63);
      int kt = (int)((f >> 9) & 7), jt = (int)(f >> 12);
      int n = jt * 16 + (l & 15), k = kt * 32 + (l >> 4) * 8 + e;
      ((_Float16*)(wsb + O_F_NHH0))[idx] =
          (_Float16)p.big_src[mi][(size_t)n * 256 + k];
      continue;
    }
    idx -= NBIG;
    if (idx < NIH0) {
      int mi = (int)(idx >> 15);
      size_t f = idx & 32767;
      int e = (int)(f & 7), l = (int)((f >> 3) & 63), jt = (int)(f >> 9);
      int n = jt * 16 + (l & 15), k = (l >> 4) * 8 + e;
      ((_Float16*)(wsb + O_F_NIH0))[idx] =
          (_Float16)(k < 6 ? p.ih0_src[mi][(size_t)n * 6 + k] : 0.f);
      continue;
    }
    idx -= NIH0;
    if (idx < NBC) {
      int li = (int)(idx >> 10), jj = (int)(idx & 1023);
      ((float*)(wsb + B_BC))[idx] = p.bih[li][jj] + p.bhh[li][jj];
      continue;
    }
    idx -= NBC;
    if (idx < NATT) {
      int mi = (int)(idx >> 16);
      size_t f = idx & 65535;
      int k = (int)(f >> 8), c = (int)(f & 255);
      ((float*)(wsb + B_ATT))[idx] = p.att_src[mi][(size_t)c * 256 + k];
      continue;
    }
    idx -= NATT;
    if (idx < NWCT) {
      int dt = (int)(idx / (512 * 256));
      size_t f = idx - (size_t)dt * 512 * 256;
      int c = (int)(f >> 8), o = (int)(f & 255);
      ((float*)(wsb + B_WCT))[idx] = p.Wconv[(size_t)o * 1536 + (size_t)c * 3 + dt];
      continue;
    }
    idx -= NWCT;
    {
      int k = (int)(idx >> 10), j = (int)(idx & 1023);
      ((float*)(wsb + B_DIH0T))[idx] = p.big_src[9][(size_t)j * 256 + k];
    }
  }
}

// ---------------- building blocks ----------------
DEV float fsig(float x) { return 1.f / (1.f + __expf(-x)); }
DEV float ftanh(float x) { return 1.f - 2.f / (__expf(2.f * x) + 1.f); }

DEV void loadB8(f16x8 (&dst)[8], const _Float16* __restrict__ WB, int kt,
                int w, int l) {
#pragma unroll
  for (int q = 0; q < 8; ++q) {
    int jt = (q >> 1) * 16 + w * 2 + (q & 1);
    dst[q] = *(const f16x8*)(WB + ((size_t)(jt * 8 + kt) * 64 + l) * 8);
  }
}
DEV void loadB8_ih0(f16x8 (&dst)[8], const _Float16* __restrict__ WB, int w,
                    int l) {
#pragma unroll
  for (int q = 0; q < 8; ++q) {
    int jt = (q >> 1) * 16 + w * 2 + (q & 1);
    dst[q] = *(const f16x8*)(WB + ((size_t)jt * 64 + l) * 8);
  }
}

template <int MT>
DEV void mm_chunk(f32x4 (&acc)[MT][4][2], const _Float16* Hhi,
                  const _Float16* Hlo, int kt, const f16x8 (&bb)[8], int m15,
                  int khi) {
  f16x8 ah[MT], al[MT];
#pragma unroll
  for (int mt = 0; mt < MT; ++mt) {
    int off = (mt * 16 + m15) * 264 + kt * 32 + khi;
    ah[mt] = *(const f16x8*)(Hhi + off);
    al[mt] = *(const f16x8*)(Hlo + off);
  }
#pragma unroll
  for (int q = 0; q < 8; ++q) {
    int g = q >> 1, t2 = q & 1;
#pragma unroll
    for (int mt = 0; mt < MT; ++mt) {
      acc[mt][g][t2] = __builtin_amdgcn_mfma_f32_16x16x32_f16(
          ah[mt], bb[q], acc[mt][g][t2], 0, 0, 0);
      acc[mt][g][t2] = __builtin_amdgcn_mfma_f32_16x16x32_f16(
          al[mt], bb[q], acc[mt][g][t2], 0, 0, 0);
    }
  }
}

template <int MT>
DEV void acc_init(f32x4 (&acc)[MT][4][2], const float (&b)[4][2]) {
#pragma unroll
  for (int mt = 0; mt < MT; ++mt)
#pragma unroll
    for (int g = 0; g < 4; ++g)
#pragma unroll
      for (int t2 = 0; t2 < 2; ++t2) {
        f32x4 v = {b[g][t2], b[g][t2], b[g][t2], b[g][t2]};
        acc[mt][g][t2] = v;
      }
}

template <int MT>
DEV void cell_compute(f32x4 (&acc)[MT][4][2], f32x4 (&c)[MT][2],
                      float (&hv)[MT][2][4]) {
#pragma unroll
  for (int mt = 0; mt < MT; ++mt)
#pragma unroll
    for (int t2 = 0; t2 < 2; ++t2)
#pragma unroll
      for (int r = 0; r < 4; ++r) {
        float iv = fsig(acc[mt][0][t2][r]);
        float fv = fsig(acc[mt][1][t2][r]);
        float gv = ftanh(acc[mt][2][t2][r]);
        float ov = fsig(acc[mt][3][t2][r]);
        float cv = fv * c[mt][t2][r] + iv * gv;
        c[mt][t2][r] = cv;
        hv[mt][t2][r] = ov * ftanh(cv);
      }
}

template <int MT>
DEV void writeH(const float (&hv)[MT][2][4], _Float16* Hhi, _Float16* Hlo,
                int w, int l) {
  const int rbase = (l >> 4) * 4, m15 = l & 15;
#pragma unroll
  for (int mt = 0; mt < MT; ++mt)
#pragma unroll
    for (int t2 = 0; t2 < 2; ++t2)
#pragma unroll
      for (int r = 0; r < 4; ++r) {
        int m = mt * 16 + rbase + r, col = w * 32 + t2 * 16 + m15;
        float hvv = hv[mt][t2][r];
        _Float16 hi = (_Float16)hvv;
        Hhi[m * 264 + col] = hi;
        Hlo[m * 264 + col] = (_Float16)(hvv - (float)hi);
      }
}

// chunk macro: consume bc, prefetch (WBn,ktn) into bn
#define CHUNK(bc, bn, WBn, ktn, Hhi, Hlo, kt)   \
  loadB8(bn, WBn, ktn, w, l);                   \
  mm_chunk<MTC>(acc, Hhi, Hlo, kt, bc, m15, khi);
// 8-chunk group over kt=0..7 reading (Hhi,Hlo); prefetch chain ends at (WBn,0)
#define G8(WBc, WBn, Hhi, Hlo)                  \
  CHUNK(bpA, bpB, WBc, 1, Hhi, Hlo, 0)          \
  CHUNK(bpB, bpA, WBc, 2, Hhi, Hlo, 1)          \
  CHUNK(bpA, bpB, WBc, 3, Hhi, Hlo, 2)          \
  CHUNK(bpB, bpA, WBc, 4, Hhi, Hlo, 3)          \
  CHUNK(bpA, bpB, WBc, 5, Hhi, Hlo, 4)          \
  CHUNK(bpB, bpA, WBc, 6, Hhi, Hlo, 5)          \
  CHUNK(bpA, bpB, WBc, 7, Hhi, Hlo, 6)          \
  CHUNK(bpB, bpA, WBn, 0, Hhi, Hlo, 7)

// ---------------- encoder: fused ego+nbr 2-layer LSTM (MFMA, pipelined) ----------------
// __launch_bounds__(512, 1): 8-wave block still forces 2 waves/SIMD residency,
// so the allocator gets the full 256-VGPR budget -> prefetch banks stay in regs.
__global__ __launch_bounds__(512, 1) void encoder_kernel(Par p) {
  constexpr int MTC = 2;
  __shared__ _Float16 Hs[2][2][32][264];  // [layer][hi/lo][m][k pad]
  __shared__ _Float16 XF[2][512];         // [mt][lane*8] A-frag of x (K pad 32)
  const int tid = threadIdx.x, w = tid >> 6, l = tid & 63;
  const int m15 = l & 15, khi = (l >> 4) * 8;
  const int bid = blockIdx.x;
  const bool ego = ((bid & 7) == 0) && (bid < 64);
  int nid = 0, eidx = 0;
  if (ego) {
    eidx = bid >> 3;
  } else {
    int nb = (bid + 7) >> 3;
    if (nb > 8) nb = 8;
    nid = bid - nb;
  }
  char* wsb = (char*)p.ws;
  const _Float16* WB_hh0 = (const _Float16*)(wsb + (ego ? O_F_EHH0 : O_F_NHH0));
  const _Float16* WB_ih1 = (const _Float16*)(wsb + (ego ? O_F_EIH1 : O_F_NIH1));
  const _Float16* WB_hh1 = (const _Float16*)(wsb + (ego ? O_F_EHH1 : O_F_NHH1));
  const _Float16* WB_ih0 = (const _Float16*)(wsb + (ego ? O_F_EIH0 : O_F_NIH0));

  for (int i = tid; i < 2 * 2 * 32 * 264; i += 512)
    ((_Float16*)Hs)[i] = (_Float16)0.f;
  for (int i = tid; i < 1024; i += 512) ((_Float16*)XF)[i] = (_Float16)0.f;

  const float* bcb = (const float*)(wsb + B_BC) + (ego ? 2048 : 0);
  float b0v[4][2], b1v[4][2];
#pragma unroll
  for (int g = 0; g < 4; ++g)
#pragma unroll
    for (int t2 = 0; t2 < 2; ++t2) {
      int j = g * 256 + w * 32 + t2 * 16 + m15;
      b0v[g][t2] = bcb[j];
      b1v[g][t2] = bcb[1024 + j];
    }

  // x staging: tid<192 -> (m32 0..31, kx 0..5)
  const int m32 = tid / 6, kx = tid - m32 * 6;
  const float* xp = nullptr;
  int xslot = 0;
  if (tid < 192) {
    int row;
    if (!ego) {
      int n = nid * 32 + m32;
      int q = n / 19;
      row = q * 20 + 1 + (n - q * 19);
    } else {
      row = (eidx * 32 + m32) * 20;
    }
    xp = p.x + (size_t)row * XROW + kx;
    xslot = (m32 >> 4) * 512 + (m32 & 15) * 8 + kx;
  }

  __syncthreads();
  if (tid < 192) ((_Float16*)XF)[xslot] = (_Float16)xp[0];

  f16x8 bI[8], bpA[8], bpB[8];
  loadB8_ih0(bI, WB_ih0, w, l);   // t-invariant, lives in regs all 50 steps
  loadB8(bpA, WB_hh0, 0, w, l);   // prologue of the prefetch chain
  __syncthreads();

  f32x4 c0[2][2] = {}, c1[2][2] = {};
  float h0v[2][2][4], h1v[2][2][4];

  for (int t = 0; t < T_; ++t) {
    // ---- layer 0 ----
    f32x4 acc[MTC][4][2];
    acc_init<MTC>(acc, b0v);
    {  // ih0 chunk
      f16x8 a0 = *(const f16x8*)(&XF[0][l * 8]);
      f16x8 a1 = *(const f16x8*)(&XF[1][l * 8]);
#pragma unroll
      for (int q = 0; q < 8; ++q) {
        acc[0][q >> 1][q & 1] = __builtin_amdgcn_mfma_f32_16x16x32_f16(
            a0, bI[q], acc[0][q >> 1][q & 1], 0, 0, 0);
        acc[1][q >> 1][q & 1] = __builtin_amdgcn_mfma_f32_16x16x32_f16(
            a1, bI[q], acc[1][q >> 1][q & 1], 0, 0, 0);
      }
    }
    G8(WB_hh0, WB_ih1, &Hs[0][0][0][0], &Hs[0][1][0][0])
    cell_compute<MTC>(acc, c0, h0v);
    __syncthreads();  // B1: all reads of Hs[0] done
    writeH<MTC>(h0v, &Hs[0][0][0][0], &Hs[0][1][0][0], w, l);
    if (t < T_ - 1 && tid < 192)
      ((_Float16*)XF)[xslot] = (_Float16)xp[(t + 1) * IN_];
    __syncthreads();  // B2: h0_new + x_{t+1} visible

    // ---- layer 1 ----
    acc_init<MTC>(acc, b1v);
    G8(WB_ih1, WB_hh1, &Hs[0][0][0][0], &Hs[0][1][0][0])   // h0 NEW
    G8(WB_hh1, WB_hh0, &Hs[1][0][0][0], &Hs[1][1][0][0])   // h1 OLD; wraps to next step's hh0
    cell_compute<MTC>(acc, c1, h1v);
    __syncthreads();  // B3: reads of Hs[1] done
    writeH<MTC>(h1v, &Hs[1][0][0][0], &Hs[1][1][0][0], w, l);
    if (t >= T_ - 2) {  // only t=48,49 consumed downstream
      int tg = t - (T_ - 2);
      const int rbase = (l >> 4) * 4;
#pragma unroll
      for (int mt = 0; mt < 2; ++mt)
#pragma unroll
        for (int t2 = 0; t2 < 2; ++t2)
#pragma unroll
          for (int r = 0; r < 4; ++r) {
            int mloc = mt * 16 + rbase + r, col = w * 32 + t2 * 16 + m15;
            if (!ego) {
              int n = nid * 32 + mloc;
              ((float*)(wsb + B_NBRH1))[((size_t)tg * NB_ + n) * H_ + col] =
                  h1v[mt][t2][r];
            } else {
              int b = eidx * 32 + mloc;
              ((float*)(wsb + B_COMB))[((size_t)tg * B_ + b) * 512 + col] =
                  h1v[mt][t2][r];
            }
          }
    }
    __syncthreads();  // B4
  }
}

// ---------------- attention at t=48,49 (one block per (t2,b)) ----------------
__global__ __launch_bounds__(256) void attn_kernel(Par p) {
  __shared__ float kk[NN_][H_];
  __shared__ float vv[NN_][H_];
  __shared__ float e[H_];
  __shared__ float q[H_];
  __shared__ float att[H_];
  __shared__ float sc[NH_][NN_];
  const int tid = threadIdx.x;
  const int bid = blockIdx.x;
  const int t2 = bid >> 8, b = bid & 255;
  char* wsb = (char*)p.ws;
  const float* attw = (const float*)(wsb + B_ATT);
  float* comb = (float*)(wsb + B_COMB);

  e[tid] = comb[((size_t)t2 * B_ + b) * 512 + tid];
  __syncthreads();
  {
    float a = p.bq[tid];
    const float* Wq = attw + tid;
    for (int k0 = 0; k0 < H_; k0 += 4) {
      const float4 e4 = *reinterpret_cast<const float4*>(&e[k0]);
      a = fmaf(Wq[(size_t)k0 * 256], e4.x, a);
      a = fmaf(Wq[(size_t)(k0 + 1) * 256], e4.y, a);
      a = fmaf(Wq[(size_t)(k0 + 2) * 256], e4.z, a);
      a = fmaf(Wq[(size_t)(k0 + 3) * 256], e4.w, a);
    }
    q[tid] = a;
  }
  {
    float ak[NN_], av[NN_];
#pragma unroll
    for (int n = 0; n < NN_; ++n) { ak[n] = p.bk[tid]; av[n] = p.bv[tid]; }
    const float* Wk = attw + 65536 + tid;
    const float* Wv = attw + 2 * 65536 + tid;
    const float* hb = (const float*)(wsb + B_NBRH1) +
                      ((size_t)t2 * NB_ + (size_t)b * NN_) * H_;
    for (int k0 = 0; k0 < H_; k0 += 4) {
      float wk0 = Wk[(size_t)k0 * 256], wk1 = Wk[(size_t)(k0 + 1) * 256];
      float wk2 = Wk[(size_t)(k0 + 2) * 256], wk3 = Wk[(size_t)(k0 + 3) * 256];
      float wv0 = Wv[(size_t)k0 * 256], wv1 = Wv[(size_t)(k0 + 1) * 256];
      float wv2 = Wv[(size_t)(k0 + 2) * 256], wv3 = Wv[(size_t)(k0 + 3) * 256];
#pragma unroll
      for (int n = 0; n < NN_; ++n) {
        const float4 h4 =
            *reinterpret_cast<const float4*>(hb + (size_t)n * H_ + k0);
        ak[n] = fmaf(wk0, h4.x, ak[n]);
        ak[n] = fmaf(wk1, h4.y, ak[n]);
        ak[n] = fmaf(wk2, h4.z, ak[n]);
        ak[n] = fmaf(wk3, h4.w, ak[n]);
        av[n] = fmaf(wv0, h4.x, av[n]);
        av[n] = fmaf(wv1, h4.y, av[n]);
        av[n] = fmaf(wv2, h4.z, av[n]);
        av[n] = fmaf(wv3, h4.w, av[n]);
      }
    }
#pragma unroll
    for (int n = 0; n < NN_; ++n) { kk[n][tid] = ak[n]; vv[n][tid] = av[n]; }
  }
  __syncthreads();
  if (tid < NH_ * NN_) {
    int h = tid / NN_, n = tid - h * NN_;
    float s = 0.f;
#pragma unroll
    for (int d = 0; d < 32; ++d) s = fmaf(q[h * 32 + d], kk[n][h * 32 + d], s);
    sc[h][n] = s * 0.17677669529663687f;
  }
  __syncthreads();
  if (tid < NH_) {
    float mx = sc[tid][0];
#pragma unroll
    for (int n = 1; n < NN_; ++n) mx = fmaxf(mx, sc[tid][n]);
    float den = 0.f, wn[NN_];
#pragma unroll
    for (int n = 0; n < NN_; ++n) {
      wn[n] = __expf(sc[tid][n] - mx);
      den += wn[n];
    }
    float r = 1.f / den;
#pragma unroll
    for (int n = 0; n < NN_; ++n) sc[tid][n] = wn[n] * r;
  }
  __syncthreads();
  {
    int h = tid >> 5;
    float a = 0.f;
#pragma unroll
    for (int n = 0; n < NN_; ++n) a = fmaf(sc[h][n], vv[n][tid], a);
    att[tid] = a;
  }
  __syncthreads();
  {
    float a = p.bao[tid];
    const float* Wao = attw + 3 * 65536 + tid;
    for (int k0 = 0; k0 < H_; k0 += 4) {
      const float4 a4 = *reinterpret_cast<const float4*>(&att[k0]);
      a = fmaf(Wao[(size_t)k0 * 256], a4.x, a);
      a = fmaf(Wao[(size_t)(k0 + 1) * 256], a4.y, a);
      a = fmaf(Wao[(size_t)(k0 + 2) * 256], a4.z, a);
      a = fmaf(Wao[(size_t)(k0 + 3) * 256], a4.w, a);
    }
    comb[((size_t)t2 * B_ + b) * 512 + 256 + tid] = a;
  }
}

// -------- conv (only t=49 output live) + decoder layer-0 x-part --------
__global__ __launch_bounds__(256) void conv_kernel(Par p) {
  __shared__ float cl[2][512];
  __shared__ float tf[H_];
  const int b = blockIdx.x, tid = threadIdx.x;
  char* wsb = (char*)p.ws;
  const float* comb = (const float*)(wsb + B_COMB);
  for (int idx = tid; idx < 1024; idx += 256) {
    int t2 = idx >> 9, c = idx & 511;
    cl[t2][c] = comb[((size_t)t2 * B_ + b) * 512 + c];
  }
  __syncthreads();
  {
    float a = p.bconv[tid];
    const float* W0 = (const float*)(wsb + B_WCT) + tid;
    const float* W1 = W0 + 512 * 256;
    for (int c = 0; c < 512; ++c) {
      a = fmaf(cl[0][c], W0[(size_t)c * 256], a);
      a = fmaf(cl[1][c], W1[(size_t)c * 256], a);
    }
    tf[tid] = a;
  }
  __syncthreads();
  {
    float accp[4];
    const float* bcd0 = (const float*)(wsb + B_BC) + 4096;
#pragma unroll
    for (int g = 0; g < 4; ++g) accp[g] = bcd0[g * 256 + tid];
    const float* Wt = (const float*)(wsb + B_DIH0T) + tid;
    for (int k0 = 0; k0 < H_; k0 += 4) {
      const float4 t4 = *reinterpret_cast<const float4*>(&tf[k0]);
      float tv[4] = {t4.x, t4.y, t4.z, t4.w};
#pragma unroll
      for (int kq = 0; kq < 4; ++kq) {
        const float* wp = Wt + (size_t)(k0 + kq) * G_;
        accp[0] = fmaf(wp[0], tv[kq], accp[0]);
        accp[1] = fmaf(wp[256], tv[kq], accp[1]);
        accp[2] = fmaf(wp[512], tv[kq], accp[2]);
        accp[3] = fmaf(wp[768], tv[kq], accp[3]);
      }
    }
    float* pre0 = (float*)(wsb + B_PRE0);
#pragma unroll
    for (int g = 0; g < 4; ++g) pre0[(size_t)b * G_ + g * 256 + tid] = accp[g];
  }
}

// ---------------- decoder: 2-layer LSTM, 60 steps (MFMA, pipelined) + head ----------------
__global__ __launch_bounds__(512, 1) void decoder_kernel(Par p) {
  constexpr int MTC = 1;
  __shared__ _Float16 Hs[2][2][16][264];
  const int tid = threadIdx.x, w = tid >> 6, l = tid & 63;
  const int m15 = l & 15, khi = (l >> 4) * 8;
  const int bid = blockIdx.x;
  char* wsb = (char*)p.ws;
  const _Float16* WB_hh0 = (const _Float16*)(wsb + O_F_DHH0);
  const _Float16* WB_ih1 = (const _Float16*)(wsb + O_F_DIH1);
  const _Float16* WB_hh1 = (const _Float16*)(wsb + O_F_DHH1);

  for (int i = tid; i < 2 * 2 * 16 * 264; i += 512)
    ((_Float16*)Hs)[i] = (_Float16)0.f;

  const float* bcd1 = (const float*)(wsb + B_BC) + 5120;
  float b1v[4][2];
  f32x4 pre[4][2];
  {
    const float* pre0 = (const float*)(wsb + B_PRE0);
    const int rbase = (l >> 4) * 4;
#pragma unroll
    for (int g = 0; g < 4; ++g)
#pragma unroll
      for (int t2 = 0; t2 < 2; ++t2) {
        int j = g * 256 + w * 32 + t2 * 16 + m15;
        b1v[g][t2] = bcd1[j];
#pragma unroll
        for (int r = 0; r < 4; ++r)
          pre[g][t2][r] = pre0[(size_t)(bid * 16 + rbase + r) * G_ + j];
      }
  }
  const int hm = tid >> 5, hpp = (tid >> 4) & 1, hkc = tid & 15;
  float wr[16], bo;
  {
#pragma unroll
    for (int e2 = 0; e2 < 16; ++e2) wr[e2] = p.Wout[hpp * 256 + hkc * 16 + e2];
    bo = p.bout[hpp];
  }

  f16x8 bpA[8], bpB[8];
  loadB8(bpA, WB_hh0, 0, w, l);
  f32x4 c0[1][2] = {}, c1[1][2] = {};
  float h0v[1][2][4], h1v[1][2][4];
  __syncthreads();

  for (int t = 0; t < DT_; ++t) {
    f32x4 acc[MTC][4][2];
#pragma unroll
    for (int g = 0; g < 4; ++g)
#pragma unroll
      for (int t2 = 0; t2 < 2; ++t2) acc[0][g][t2] = pre[g][t2];
    G8(WB_hh0, WB_ih1, &Hs[0][0][0][0], &Hs[0][1][0][0])
    cell_compute<MTC>(acc, c0, h0v);
    __syncthreads();  // B1
    writeH<MTC>(h0v, &Hs[0][0][0][0], &Hs[0][1][0][0], w, l);
    __syncthreads();  // B2
    acc_init<MTC>(acc, b1v);
    G8(WB_ih1, WB_hh1, &Hs[0][0][0][0], &Hs[0][1][0][0])
    G8(WB_hh1, WB_hh0, &Hs[1][0][0][0], &Hs[1][1][0][0])
    cell_compute<MTC>(acc, c1, h1v);
    __syncthreads();  // B3
    writeH<MTC>(h1v, &Hs[1][0][0][0], &Hs[1][1][0][0], w, l);
    __syncthreads();  // B4
    {  // head: pred[m][pp] = (h1hi+h1lo) . Wout[pp] + bout[pp]
      const _Float16* h1h = &Hs[1][0][hm][hkc * 16];
      const _Float16* h1l = &Hs[1][1][hm][hkc * 16];
      f16x8 a0 = *(const f16x8*)(h1h), a1 = *(const f16x8*)(h1h + 8);
      f16x8 q0 = *(const f16x8*)(h1l), q1 = *(const f16x8*)(h1l + 8);
      float s = 0.f;
#pragma unroll
      for (int e2 = 0; e2 < 8; ++e2) {
        s = fmaf((float)a0[e2] + (float)q0[e2], wr[e2], s);
        s = fmaf((float)a1[e2] + (float)q1[e2], wr[8 + e2], s);
      }
#pragma unroll
      for (int off = 1; off < 16; off <<= 1) s += __shfl_xor(s, off);
      if ((tid & 15) == 0)
        p.out[((size_t)(bid * 16 + hm) * DT_ + t) * 2 + hpp] = s + bo;
    }
  }
}

// ---------------- host launcher ----------------
extern "C" void kernel_launch(void* const* d_in, const int* in_sizes, int n_in,
                              void* d_out, int out_size, void* d_ws,
                              size_t ws_size, hipStream_t stream) {
  (void)in_sizes; (void)n_in; (void)out_size; (void)ws_size;
  auto F = [&](int i) { return (const float*)d_in[i]; };
  Par p{};
  p.x = F(0);
  p.big_src[0] = F(10);  // nbr_Whh0
  p.big_src[1] = F(13);  // nbr_Wih1
  p.big_src[2] = F(14);  // nbr_Whh1
  p.big_src[3] = F(2);   // ego_Whh0
  p.big_src[4] = F(5);   // ego_Wih1
  p.big_src[5] = F(6);   // ego_Whh1
  p.big_src[6] = F(18);  // dec_Whh0
  p.big_src[7] = F(21);  // dec_Wih1
  p.big_src[8] = F(22);  // dec_Whh1
  p.big_src[9] = F(17);  // dec_Wih0
  p.ih0_src[0] = F(9);   // nbr_Wih0
  p.ih0_src[1] = F(1);   // ego_Wih0
  p.att_src[0] = F(25); p.att_src[1] = F(26);
  p.att_src[2] = F(27); p.att_src[3] = F(28);
  p.Wconv = F(33);
  p.bih[0] = F(11); p.bhh[0] = F(12);
  p.bih[1] = F(15); p.bhh[1] = F(16);
  p.bih[2] = F(3);  p.bhh[2] = F(4);
  p.bih[3] = F(7);  p.bhh[3] = F(8);
  p.bih[4] = F(19); p.bhh[4] = F(20);
  p.bih[5] = F(23); p.bhh[5] = F(24);
  p.bq = F(29); p.bk = F(30); p.bv = F(31); p.bao = F(32);
  p.bconv = F(34); p.Wout = F(35); p.bout = F(36);
  p.ws = (float*)d_ws;
  p.out = (float*)d_out;

  hipLaunchKernelGGL(prep_kernel, dim3(1024), dim3(256), 0, stream, p);
  hipLaunchKernelGGL(encoder_kernel, dim3(NBLK_ENC), dim3(512), 0, stream, p);
  hipLaunchKernelGGL(attn_kernel, dim3(512), dim3(256), 0, stream, p);
  hipLaunchKernelGGL(conv_kernel, dim3(B_), dim3(256), 0, stream, p);
  hipLaunchKernelGGL(decoder_kernel, dim3(NBLK_DEC), dim3(512), 0, stream, p);
}